// Round 1
// baseline (1166.831 us; speedup 1.0000x reference)
//
#include <hip/hip_runtime.h>
#include <hip/hip_bf16.h>

// Problem constants
#define TT   2048   // B*S tokens
#define HH   2048   // hidden dim
#define SEQ  1024
#define NHQ  16
#define NKVH 8
#define HDD  128

typedef __attribute__((ext_vector_type(8))) short short8;
typedef __attribute__((ext_vector_type(4))) float f32x4;

// float -> bf16 bits. All values we store are small integers (|v| <= 128),
// exactly representable in bf16, so truncation is exact.
static __device__ __forceinline__ unsigned short f2bf(float f) {
  return (unsigned short)(__float_as_uint(f) >> 16);
}

// ---------------------------------------------------------------------------
// K1: per-row act_quant: scale = 127/clip(amax,1e-5); xq = clip(rint(x*s),-128,127)
// store integer values as bf16; as_inv[row] = clip(amax,1e-5)/127
// ---------------------------------------------------------------------------
__global__ __launch_bounds__(256) void k_actquant(const float* __restrict__ x,
                                                  unsigned short* __restrict__ xq,
                                                  float* __restrict__ as_inv) {
  int row = blockIdx.x;
  const float* xr = x + (size_t)row * HH;
  float amax = 0.f;
  for (int i = threadIdx.x; i < HH; i += 256) amax = fmaxf(amax, fabsf(xr[i]));
  __shared__ float red[256];
  red[threadIdx.x] = amax;
  __syncthreads();
  for (int s = 128; s > 0; s >>= 1) {
    if (threadIdx.x < s) red[threadIdx.x] = fmaxf(red[threadIdx.x], red[threadIdx.x + s]);
    __syncthreads();
  }
  float am = fmaxf(red[0], 1e-5f);
  float scale = 127.f / am;
  if (threadIdx.x == 0) as_inv[row] = am / 127.f;
  unsigned short* xqr = xq + (size_t)row * HH;
  for (int i = threadIdx.x; i < HH; i += 256) {
    float v = rintf(xr[i] * scale);
    v = fminf(fmaxf(v, -128.f), 127.f);
    xqr[i] = f2bf(v);
  }
}

// ---------------------------------------------------------------------------
// K2: deterministic partial |w| sums (f64), 256 blocks x 256 threads
// ---------------------------------------------------------------------------
__global__ __launch_bounds__(256) void k_absum(const float* __restrict__ w, int n,
                                               double* __restrict__ part) {
  double s = 0.0;
  for (int i = blockIdx.x * 256 + threadIdx.x; i < n; i += 256 * 256)
    s += (double)fabsf(w[i]);
  __shared__ double red[256];
  red[threadIdx.x] = s;
  __syncthreads();
  for (int st = 128; st > 0; st >>= 1) {
    if (threadIdx.x < st) red[threadIdx.x] += red[threadIdx.x + st];
    __syncthreads();
  }
  if (threadIdx.x == 0) part[blockIdx.x] = red[0];
}

// K2b: finalize the 4 weight scales: wsc[i] = clip(mean|w_i|, 1e-5)
__global__ __launch_bounds__(256) void k_wscale(const double* __restrict__ part,
                                                float* __restrict__ wsc) {
  __shared__ double red[256];
  const double nvals[4] = {4194304.0, 2097152.0, 2097152.0, 4194304.0};
  for (int w = 0; w < 4; ++w) {
    red[threadIdx.x] = part[w * 256 + threadIdx.x];
    __syncthreads();
    for (int st = 128; st > 0; st >>= 1) {
      if (threadIdx.x < st) red[threadIdx.x] += red[threadIdx.x + st];
      __syncthreads();
    }
    if (threadIdx.x == 0) {
      float mean = (float)(red[0] / nvals[w]);
      wsc[w] = fmaxf(mean, 1e-5f);
    }
    __syncthreads();
  }
}

// ---------------------------------------------------------------------------
// K3: ternary weight quant: wt = clip(rint(w/wsc),-1,1) as bf16
// ---------------------------------------------------------------------------
__global__ __launch_bounds__(256) void k_wquant(const float* __restrict__ w,
                                                unsigned short* __restrict__ wt,
                                                const float* __restrict__ wscp, int n) {
  float inv = 1.0f / *wscp;
  for (int i = blockIdx.x * blockDim.x + threadIdx.x; i < n; i += gridDim.x * blockDim.x) {
    float v = rintf(w[i] * inv);
    v = fminf(fmaxf(v, -1.f), 1.f);
    wt[i] = f2bf(v);
  }
}

// ---------------------------------------------------------------------------
// K4: bf16 MFMA NT-GEMM: C[m][n] = (sum_k A[m][k]*B[n][k]) * as_inv[m] * (*wscp)
// A: [2048][2048] bf16 (int-valued), B: [N][2048] bf16 (ternary). Exact int math.
// block = 256 thr = 4 waves (2x2), wave tile 32x32 (2x2 MFMA frags)
// ---------------------------------------------------------------------------
__global__ __launch_bounds__(256) void k_gemm_nt(const unsigned short* __restrict__ A,
                                                 const unsigned short* __restrict__ Bw,
                                                 float* __restrict__ C, int N,
                                                 const float* __restrict__ as_inv,
                                                 const float* __restrict__ wscp) {
  const int K = HH;
  int wave = threadIdx.x >> 6;
  int lane = threadIdx.x & 63;
  int wm = wave >> 1, wn = wave & 1;
  int bm = blockIdx.y * 64 + wm * 32;
  int bn = blockIdx.x * 64 + wn * 32;
  int r = lane & 15, g = lane >> 4;   // frag row/col, k-group
  f32x4 acc[2][2] = {};
  const unsigned short* Ab = A + (size_t)(bm + r) * K + g * 8;
  const unsigned short* Bb = Bw + (size_t)(bn + r) * K + g * 8;
  for (int k0 = 0; k0 < K; k0 += 32) {
    short8 af[2], bf[2];
    af[0] = *(const short8*)(Ab + k0);
    af[1] = *(const short8*)(Ab + (size_t)16 * K + k0);
    bf[0] = *(const short8*)(Bb + k0);
    bf[1] = *(const short8*)(Bb + (size_t)16 * K + k0);
#pragma unroll
    for (int mi = 0; mi < 2; ++mi)
#pragma unroll
      for (int ni = 0; ni < 2; ++ni)
        acc[mi][ni] = __builtin_amdgcn_mfma_f32_16x16x32_bf16(af[mi], bf[ni], acc[mi][ni], 0, 0, 0);
  }
  float wsv = *wscp;
#pragma unroll
  for (int mi = 0; mi < 2; ++mi) {
#pragma unroll
    for (int rr = 0; rr < 4; ++rr) {
      int row = bm + mi * 16 + g * 4 + rr;   // C/D: col=lane&15, row=(lane>>4)*4+reg
      float sc = as_inv[row] * wsv;
#pragma unroll
      for (int ni = 0; ni < 2; ++ni)
        C[(size_t)row * N + bn + ni * 16 + r] = acc[mi][ni][rr] * sc;
    }
  }
}

// ---------------------------------------------------------------------------
// K5: fused rmsnorm (over HD=128) + rope, in place. postscale folds 1/sqrt(HD) for q.
// grid (TT, nheads), block 128
// ---------------------------------------------------------------------------
__global__ __launch_bounds__(128) void k_normrope(float* __restrict__ t,
                                                  const float* __restrict__ nw,
                                                  const float* __restrict__ cs,
                                                  const float* __restrict__ sn,
                                                  int nh, float postscale) {
  int tok = blockIdx.x, h = blockIdx.y;
  int s = tok & (SEQ - 1);
  float* row = t + ((size_t)tok * nh + h) * HDD;
  int d = threadIdx.x;
  float v = row[d];
  __shared__ float red[128];
  red[d] = v * v;
  __syncthreads();
  for (int st = 64; st > 0; st >>= 1) {
    if (d < st) red[d] += red[d + st];
    __syncthreads();
  }
  float inv = rsqrtf(red[0] / 128.f + 1e-6f);
  float nv = nw[d] * (v * inv);
  int od = (d < 64) ? d + 64 : d - 64;
  float o = nw[od] * (row[od] * inv);
  float rh = (d < 64) ? -o : o;
  float res = (nv * cs[s * HDD + d] + rh * sn[s * HDD + d]) * postscale;
  __syncthreads();   // all reads of row[] done before in-place write
  row[d] = res;
}

// ---------------------------------------------------------------------------
// K6: f32 flash attention, causal, GQA (q head h -> kv head h/2)
// grid (SEQ/32, B*NH), block 256. q already scaled by 1/sqrt(HD).
// ---------------------------------------------------------------------------
__global__ __launch_bounds__(256) void k_attn(const float* __restrict__ q,
                                              const float* __restrict__ k,
                                              const float* __restrict__ v,
                                              float* __restrict__ o) {
  int qt = blockIdx.x;
  int bh = blockIdx.y;
  int b = bh >> 4, h = bh & 15;
  int kvh = h >> 1;
  int tid = threadIdx.x;
  __shared__ float Qs[32][132], Ks[32][132], Vs[32][132];
  __shared__ float Ps[32][33];
  __shared__ float m_s[32], l_s[32], c_s[32];

  for (int i = tid; i < 32 * 128; i += 256) {
    int qi = i >> 7, d = i & 127;
    Qs[qi][d] = q[((size_t)(b * SEQ + qt * 32 + qi) * NHQ + h) * HDD + d];
  }
  int qi_own = tid >> 3;
  int d0 = (tid & 7) * 16;
  float acc[16];
#pragma unroll
  for (int i = 0; i < 16; ++i) acc[i] = 0.f;
  if (tid < 32) { m_s[tid] = -INFINITY; l_s[tid] = 0.f; }
  __syncthreads();

  for (int kt = 0; kt <= qt; ++kt) {
    for (int i = tid; i < 32 * 128; i += 256) {
      int ki = i >> 7, d = i & 127;
      size_t base = ((size_t)(b * SEQ + kt * 32 + ki) * NKVH + kvh) * HDD + d;
      Ks[ki][d] = k[base];
      Vs[ki][d] = v[base];
    }
    __syncthreads();
    // scores: 4 per thread
    {
      int qi = tid >> 3;
      float sres[4];
#pragma unroll
      for (int c = 0; c < 4; ++c) {
        int ki = (tid & 7) + 8 * c;
        float s = 0.f;
#pragma unroll 8
        for (int d = 0; d < 128; d += 4) {
          float4 qv = *(float4*)&Qs[qi][d];
          float4 kv = *(float4*)&Ks[ki][d];
          s += qv.x * kv.x + qv.y * kv.y + qv.z * kv.z + qv.w * kv.w;
        }
        int gk = kt * 32 + ki, gq = qt * 32 + qi;
        sres[c] = (gk > gq) ? -INFINITY : s;
      }
#pragma unroll
      for (int c = 0; c < 4; ++c) Ps[qi][(tid & 7) + 8 * c] = sres[c];
    }
    __syncthreads();
    if (tid < 32) {
      float mold = m_s[tid];
      float mx = mold;
#pragma unroll
      for (int j = 0; j < 32; ++j) mx = fmaxf(mx, Ps[tid][j]);
      float corr = expf(mold - mx);
      float sum = 0.f;
#pragma unroll
      for (int j = 0; j < 32; ++j) {
        float p = expf(Ps[tid][j] - mx);
        Ps[tid][j] = p;
        sum += p;
      }
      l_s[tid] = l_s[tid] * corr + sum;
      m_s[tid] = mx;
      c_s[tid] = corr;
    }
    __syncthreads();
    float corr = c_s[qi_own];
#pragma unroll
    for (int i = 0; i < 16; ++i) acc[i] *= corr;
#pragma unroll 4
    for (int ki = 0; ki < 32; ++ki) {
      float p = Ps[qi_own][ki];
      const float4* vp = (const float4*)&Vs[ki][d0];
      float4 v0 = vp[0], v1 = vp[1], v2 = vp[2], v3 = vp[3];
      acc[0]  += p * v0.x; acc[1]  += p * v0.y; acc[2]  += p * v0.z; acc[3]  += p * v0.w;
      acc[4]  += p * v1.x; acc[5]  += p * v1.y; acc[6]  += p * v1.z; acc[7]  += p * v1.w;
      acc[8]  += p * v2.x; acc[9]  += p * v2.y; acc[10] += p * v2.z; acc[11] += p * v2.w;
      acc[12] += p * v3.x; acc[13] += p * v3.y; acc[14] += p * v3.z; acc[15] += p * v3.w;
    }
    __syncthreads();
  }
  float linv = 1.f / l_s[qi_own];
  size_t orow = ((size_t)(b * SEQ + qt * 32 + qi_own) * NHQ + h) * HDD + d0;
#pragma unroll
  for (int i = 0; i < 16; ++i) o[orow + i] = acc[i] * linv;
}

// ---------------------------------------------------------------------------
extern "C" void kernel_launch(void* const* d_in, const int* in_sizes, int n_in,
                              void* d_out, int out_size, void* d_ws, size_t ws_size,
                              hipStream_t stream) {
  const float* x  = (const float*)d_in[0];
  const float* cs = (const float*)d_in[1];
  const float* sn = (const float*)d_in[2];
  const float* wq = (const float*)d_in[3];
  const float* wk = (const float*)d_in[4];
  const float* wv = (const float*)d_in[5];
  const float* wo = (const float*)d_in[6];
  const float* qn = (const float*)d_in[7];
  const float* kn = (const float*)d_in[8];
  float* out = (float*)d_out;
  char* ws = (char*)d_ws;

  // workspace layout (bytes)
  size_t o_xq  = 0;                       // TT*HH bf16      8 MB
  size_t o_wqt = o_xq  + 8388608;         // 2048*2048 bf16  8 MB
  size_t o_wkt = o_wqt + 8388608;         // 1024*2048 bf16  4 MB
  size_t o_wvt = o_wkt + 4194304;         // 4 MB
  size_t o_wot = o_wvt + 4194304;         // 8 MB
  size_t o_q   = o_wot + 8388608;         // TT*2048 f32    16 MB
  size_t o_k   = o_q   + 16777216;        // TT*1024 f32     8 MB
  size_t o_v   = o_k   + 8388608;         // 8 MB
  size_t o_ao  = o_v   + 8388608;         // TT*2048 f32    16 MB
  size_t o_aq  = o_ao  + 16777216;        // TT*HH bf16      8 MB
  size_t o_as  = o_aq  + 8388608;         // TT f32
  size_t o_as2 = o_as  + 8192;
  size_t o_prt = o_as2 + 8192;            // 4*256 f64
  size_t o_wsc = o_prt + 8192;            // 4 f32

  unsigned short* xq  = (unsigned short*)(ws + o_xq);
  unsigned short* wqt = (unsigned short*)(ws + o_wqt);
  unsigned short* wkt = (unsigned short*)(ws + o_wkt);
  unsigned short* wvt = (unsigned short*)(ws + o_wvt);
  unsigned short* wot = (unsigned short*)(ws + o_wot);
  float* qb  = (float*)(ws + o_q);
  float* kb  = (float*)(ws + o_k);
  float* vb  = (float*)(ws + o_v);
  float* ao  = (float*)(ws + o_ao);
  unsigned short* aq = (unsigned short*)(ws + o_aq);
  float* asx = (float*)(ws + o_as);
  float* as2 = (float*)(ws + o_as2);
  double* prt = (double*)(ws + o_prt);
  float* wsc = (float*)(ws + o_wsc);

  // 1) activation quant of x
  k_actquant<<<TT, 256, 0, stream>>>(x, xq, asx);

  // 2) weight scales (deterministic f64 two-stage)
  k_absum<<<256, 256, 0, stream>>>(wq, 2048 * 2048, prt + 0 * 256);
  k_absum<<<256, 256, 0, stream>>>(wk, 1024 * 2048, prt + 1 * 256);
  k_absum<<<256, 256, 0, stream>>>(wv, 1024 * 2048, prt + 2 * 256);
  k_absum<<<256, 256, 0, stream>>>(wo, 2048 * 2048, prt + 3 * 256);
  k_wscale<<<1, 256, 0, stream>>>(prt, wsc);

  // 3) ternary weight quant
  k_wquant<<<512, 256, 0, stream>>>(wq, wqt, wsc + 0, 2048 * 2048);
  k_wquant<<<512, 256, 0, stream>>>(wk, wkt, wsc + 1, 1024 * 2048);
  k_wquant<<<512, 256, 0, stream>>>(wv, wvt, wsc + 2, 1024 * 2048);
  k_wquant<<<512, 256, 0, stream>>>(wo, wot, wsc + 3, 2048 * 2048);

  // 4) QKV projections (exact integer math on MFMA)
  k_gemm_nt<<<dim3(32, 32), 256, 0, stream>>>(xq, wqt, qb, 2048, asx, wsc + 0);
  k_gemm_nt<<<dim3(16, 32), 256, 0, stream>>>(xq, wkt, kb, 1024, asx, wsc + 1);
  k_gemm_nt<<<dim3(16, 32), 256, 0, stream>>>(xq, wvt, vb, 1024, asx, wsc + 2);

  // 5) rmsnorm + rope (q gets 1/sqrt(HD) folded in)
  k_normrope<<<dim3(TT, NHQ), 128, 0, stream>>>(qb, qn, cs, sn, NHQ, 0.08838834764831845f);
  k_normrope<<<dim3(TT, NKVH), 128, 0, stream>>>(kb, kn, cs, sn, NKVH, 1.0f);

  // 6) attention
  k_attn<<<dim3(SEQ / 32, 2 * NHQ), 256, 0, stream>>>(qb, kb, vb, ao);

  // 7) re-quant + output projection
  k_actquant<<<TT, 256, 0, stream>>>(ao, aq, as2);
  k_gemm_nt<<<dim3(32, 32), 256, 0, stream>>>(aq, wot, out, 2048, as2, wsc + 3);
}

// Round 2
// 707.075 us; speedup vs baseline: 1.6502x; 1.6502x over previous
//
#include <hip/hip_runtime.h>
#include <hip/hip_bf16.h>

// Problem constants
#define TT   2048   // B*S tokens
#define HH   2048   // hidden dim
#define SEQ  1024
#define NHQ  16
#define NKVH 8
#define HDD  128

typedef __attribute__((ext_vector_type(8))) short short8;
typedef __attribute__((ext_vector_type(4))) float f32x4;

static __device__ __forceinline__ unsigned short f2bf(float f) {
  return (unsigned short)(__float_as_uint(f) >> 16);   // truncate; lo-term compensates
}
static __device__ __forceinline__ float bf2f(unsigned short u) {
  return __uint_as_float(((unsigned int)u) << 16);
}

// ---------------------------------------------------------------------------
// K1: per-row act_quant
// ---------------------------------------------------------------------------
__global__ __launch_bounds__(256) void k_actquant(const float* __restrict__ x,
                                                  unsigned short* __restrict__ xq,
                                                  float* __restrict__ as_inv) {
  int row = blockIdx.x;
  const float* xr = x + (size_t)row * HH;
  float amax = 0.f;
  for (int i = threadIdx.x; i < HH; i += 256) amax = fmaxf(amax, fabsf(xr[i]));
  __shared__ float red[256];
  red[threadIdx.x] = amax;
  __syncthreads();
  for (int s = 128; s > 0; s >>= 1) {
    if (threadIdx.x < s) red[threadIdx.x] = fmaxf(red[threadIdx.x], red[threadIdx.x + s]);
    __syncthreads();
  }
  float am = fmaxf(red[0], 1e-5f);
  float scale = 127.f / am;
  if (threadIdx.x == 0) as_inv[row] = am / 127.f;
  unsigned short* xqr = xq + (size_t)row * HH;
  for (int i = threadIdx.x; i < HH; i += 256) {
    float v = rintf(xr[i] * scale);
    v = fminf(fmaxf(v, -128.f), 127.f);
    xqr[i] = f2bf(v);
  }
}

// ---------------------------------------------------------------------------
// K2: deterministic partial |w| sums (f64)
// ---------------------------------------------------------------------------
__global__ __launch_bounds__(256) void k_absum(const float* __restrict__ w, int n,
                                               double* __restrict__ part) {
  double s = 0.0;
  for (int i = blockIdx.x * 256 + threadIdx.x; i < n; i += 256 * 256)
    s += (double)fabsf(w[i]);
  __shared__ double red[256];
  red[threadIdx.x] = s;
  __syncthreads();
  for (int st = 128; st > 0; st >>= 1) {
    if (threadIdx.x < st) red[threadIdx.x] += red[threadIdx.x + st];
    __syncthreads();
  }
  if (threadIdx.x == 0) part[blockIdx.x] = red[0];
}

__global__ __launch_bounds__(256) void k_wscale(const double* __restrict__ part,
                                                float* __restrict__ wsc) {
  __shared__ double red[256];
  const double nvals[4] = {4194304.0, 2097152.0, 2097152.0, 4194304.0};
  for (int w = 0; w < 4; ++w) {
    red[threadIdx.x] = part[w * 256 + threadIdx.x];
    __syncthreads();
    for (int st = 128; st > 0; st >>= 1) {
      if (threadIdx.x < st) red[threadIdx.x] += red[threadIdx.x + st];
      __syncthreads();
    }
    if (threadIdx.x == 0) {
      float mean = (float)(red[0] / nvals[w]);
      wsc[w] = fmaxf(mean, 1e-5f);
    }
    __syncthreads();
  }
}

// ---------------------------------------------------------------------------
// K3: ternary weight quant
// ---------------------------------------------------------------------------
__global__ __launch_bounds__(256) void k_wquant(const float* __restrict__ w,
                                                unsigned short* __restrict__ wt,
                                                const float* __restrict__ wscp, int n) {
  float inv = 1.0f / *wscp;
  for (int i = blockIdx.x * blockDim.x + threadIdx.x; i < n; i += gridDim.x * blockDim.x) {
    float v = rintf(w[i] * inv);
    v = fminf(fmaxf(v, -1.f), 1.f);
    wt[i] = f2bf(v);
  }
}

// ---------------------------------------------------------------------------
// K4: bf16 MFMA NT-GEMM  C[m][n] = (sum_k A[m][k]*B[n][k]) * as_inv[m] * wsc
// ---------------------------------------------------------------------------
__global__ __launch_bounds__(256) void k_gemm_nt(const unsigned short* __restrict__ A,
                                                 const unsigned short* __restrict__ Bw,
                                                 float* __restrict__ C, int N,
                                                 const float* __restrict__ as_inv,
                                                 const float* __restrict__ wscp) {
  const int K = HH;
  int wave = threadIdx.x >> 6;
  int lane = threadIdx.x & 63;
  int wm = wave >> 1, wn = wave & 1;
  int bm = blockIdx.y * 64 + wm * 32;
  int bn = blockIdx.x * 64 + wn * 32;
  int r = lane & 15, g = lane >> 4;
  f32x4 acc[2][2] = {};
  const unsigned short* Ab = A + (size_t)(bm + r) * K + g * 8;
  const unsigned short* Bb = Bw + (size_t)(bn + r) * K + g * 8;
  for (int k0 = 0; k0 < K; k0 += 32) {
    short8 af[2], bf[2];
    af[0] = *(const short8*)(Ab + k0);
    af[1] = *(const short8*)(Ab + (size_t)16 * K + k0);
    bf[0] = *(const short8*)(Bb + k0);
    bf[1] = *(const short8*)(Bb + (size_t)16 * K + k0);
#pragma unroll
    for (int mi = 0; mi < 2; ++mi)
#pragma unroll
      for (int ni = 0; ni < 2; ++ni)
        acc[mi][ni] = __builtin_amdgcn_mfma_f32_16x16x32_bf16(af[mi], bf[ni], acc[mi][ni], 0, 0, 0);
  }
  float wsv = *wscp;
#pragma unroll
  for (int mi = 0; mi < 2; ++mi) {
#pragma unroll
    for (int rr = 0; rr < 4; ++rr) {
      int row = bm + mi * 16 + g * 4 + rr;
      float sc = as_inv[row] * wsv;
#pragma unroll
      for (int ni = 0; ni < 2; ++ni)
        C[(size_t)row * N + bn + ni * 16 + r] = acc[mi][ni][rr] * sc;
    }
  }
}

// ---------------------------------------------------------------------------
// K4b: V projection with transposed hi/lo bf16 output.
// D[n][m] = sum_k W[n][k] X[m][k];  n = kvh*128+d, m = b*1024+s
// vt_{hi,lo}[(b*1024 + n)*1024 + s]
// ---------------------------------------------------------------------------
__global__ __launch_bounds__(256) void k_gemm_vt(const unsigned short* __restrict__ W,
                                                 const unsigned short* __restrict__ X,
                                                 unsigned short* __restrict__ vth,
                                                 unsigned short* __restrict__ vtl,
                                                 const float* __restrict__ as_inv,
                                                 const float* __restrict__ wscp) {
  const int K = HH;
  int wave = threadIdx.x >> 6;
  int lane = threadIdx.x & 63;
  int wn = wave >> 1, wm = wave & 1;
  int bn = blockIdx.y * 64 + wn * 32;   // n (feature rows of W)
  int bm = blockIdx.x * 64 + wm * 32;   // m (tokens)
  int l15 = lane & 15, g = lane >> 4;
  f32x4 acc[2][2] = {};
  const unsigned short* Wb = W + (size_t)(bn + l15) * K + g * 8;
  const unsigned short* Xb = X + (size_t)(bm + l15) * K + g * 8;
  for (int k0 = 0; k0 < K; k0 += 32) {
    short8 wf[2], xf[2];
    wf[0] = *(const short8*)(Wb + k0);
    wf[1] = *(const short8*)(Wb + (size_t)16 * K + k0);
    xf[0] = *(const short8*)(Xb + k0);
    xf[1] = *(const short8*)(Xb + (size_t)16 * K + k0);
#pragma unroll
    for (int ni = 0; ni < 2; ++ni)
#pragma unroll
      for (int mi = 0; mi < 2; ++mi)
        acc[ni][mi] = __builtin_amdgcn_mfma_f32_16x16x32_bf16(wf[ni], xf[mi], acc[ni][mi], 0, 0, 0);
  }
  float wsv = *wscp;
#pragma unroll
  for (int ni = 0; ni < 2; ++ni) {
#pragma unroll
    for (int rr = 0; rr < 4; ++rr) {
      int n = bn + ni * 16 + 4 * g + rr;
#pragma unroll
      for (int mi = 0; mi < 2; ++mi) {
        int m = bm + mi * 16 + l15;
        float v = acc[ni][mi][rr] * as_inv[m] * wsv;
        unsigned short hi = f2bf(v);
        size_t addr = ((size_t)((m >> 10) * 1024 + n)) * 1024 + (m & 1023);
        vth[addr] = hi;
        vtl[addr] = f2bf(v - bf2f(hi));
      }
    }
  }
}

// ---------------------------------------------------------------------------
// K5: rmsnorm + rope -> bf16 hi/lo arrays (postscale folds 1/sqrt(HD) for q)
// ---------------------------------------------------------------------------
__global__ __launch_bounds__(128) void k_normrope(const float* __restrict__ in,
                                                  const float* __restrict__ nw,
                                                  const float* __restrict__ cs,
                                                  const float* __restrict__ sn,
                                                  unsigned short* __restrict__ oh,
                                                  unsigned short* __restrict__ ol,
                                                  int nh, float postscale) {
  int tok = blockIdx.x, h = blockIdx.y;
  int s = tok & (SEQ - 1);
  const float* row = in + ((size_t)tok * nh + h) * HDD;
  int d = threadIdx.x;
  float v = row[d];
  __shared__ float red[128];
  red[d] = v * v;
  __syncthreads();
  for (int st = 64; st > 0; st >>= 1) {
    if (d < st) red[d] += red[d + st];
    __syncthreads();
  }
  float inv = rsqrtf(red[0] / 128.f + 1e-6f);
  float nv = nw[d] * (v * inv);
  int od = (d < 64) ? d + 64 : d - 64;
  float o = nw[od] * (row[od] * inv);
  float rh = (d < 64) ? -o : o;
  float res = (nv * cs[s * HDD + d] + rh * sn[s * HDD + d]) * postscale;
  size_t oi = ((size_t)tok * nh + h) * HDD + d;
  unsigned short hi = f2bf(res);
  oh[oi] = hi;
  ol[oi] = f2bf(res - bf2f(hi));
}

// ---------------------------------------------------------------------------
// K6: MFMA flash attention, causal, GQA. 2 waves/block, 16 q-rows per wave.
// Swapped QK^T (mfma(K,Q) -> S^T: col=q, row=key), hi/lo error-compensated
// splits on Q,K,P,V. V pre-transposed [d][s]. Per-wave LDS for P transpose.
// ---------------------------------------------------------------------------
#define QW 16   // q rows per wave
__global__ __launch_bounds__(128) void k_attn_mfma(const unsigned short* __restrict__ qhp,
                                                   const unsigned short* __restrict__ qlp,
                                                   const unsigned short* __restrict__ khp,
                                                   const unsigned short* __restrict__ klp,
                                                   const unsigned short* __restrict__ vhp,
                                                   const unsigned short* __restrict__ vlp,
                                                   float* __restrict__ o) {
  int qt = gridDim.x - 1 - blockIdx.x;       // heavy (high-qt) blocks dispatch first
  int bh = blockIdx.y;
  int b = bh >> 4, h = bh & 15, kvh = h >> 1;
  int wave = threadIdx.x >> 6, lane = threadIdx.x & 63;
  int l15 = lane & 15, g = lane >> 4;
  int q0 = qt * 32 + wave * QW;
  int qglob = q0 + l15;

  __shared__ unsigned short Pl[2][2][16][40];  // [wave][hi/lo][q][key pad->40]

  // Q fragments (B-operand): lane holds Q[q=l15][c*32 + g*8 + j]
  short8 qfh[4], qfl[4];
  {
    const unsigned short* qb = qhp + ((size_t)(b * SEQ + qglob) * NHQ + h) * HDD + g * 8;
    const unsigned short* ql = qlp + ((size_t)(b * SEQ + qglob) * NHQ + h) * HDD + g * 8;
#pragma unroll
    for (int c = 0; c < 4; ++c) {
      qfh[c] = *(const short8*)(qb + c * 32);
      qfl[c] = *(const short8*)(ql + c * 32);
    }
  }

  f32x4 acc[8] = {};                 // [d-tile]; col=d=l15, row=q=4g+r
  float m_run = -INFINITY, l_run = 0.f;
  int nkv = q0 / 32 + 1;

  for (int kv = 0; kv < nkv; ++kv) {
    int kv0 = kv * 32;
    // ---- scores S^T (2 tiles of 16 keys) ----
    float sc[2][4];
#pragma unroll
    for (int t = 0; t < 2; ++t) {
      size_t koff = ((size_t)(b * SEQ + kv0 + 16 * t + l15) * NKVH + kvh) * HDD + g * 8;
      const unsigned short* kbh = khp + koff;
      const unsigned short* kbl = klp + koff;
      f32x4 s = {0.f, 0.f, 0.f, 0.f};
#pragma unroll
      for (int c = 0; c < 4; ++c) {
        short8 kfh = *(const short8*)(kbh + c * 32);
        short8 kfl = *(const short8*)(kbl + c * 32);
        s = __builtin_amdgcn_mfma_f32_16x16x32_bf16(kfh, qfh[c], s, 0, 0, 0);
        s = __builtin_amdgcn_mfma_f32_16x16x32_bf16(kfl, qfh[c], s, 0, 0, 0);
        s = __builtin_amdgcn_mfma_f32_16x16x32_bf16(kfh, qfl[c], s, 0, 0, 0);
      }
#pragma unroll
      for (int r = 0; r < 4; ++r) sc[t][r] = s[r];
    }
    // ---- causal mask (only the last KV block can clip) ----
    if (kv == nkv - 1) {
#pragma unroll
      for (int t = 0; t < 2; ++t)
#pragma unroll
        for (int r = 0; r < 4; ++r)
          if (kv0 + 16 * t + 4 * g + r > qglob) sc[t][r] = -INFINITY;
    }
    // ---- online softmax (each lane owns ONE query = l15) ----
    float mx = m_run;
#pragma unroll
    for (int t = 0; t < 2; ++t)
#pragma unroll
      for (int r = 0; r < 4; ++r) mx = fmaxf(mx, sc[t][r]);
    mx = fmaxf(mx, __shfl_xor(mx, 16));
    mx = fmaxf(mx, __shfl_xor(mx, 32));
    float corr = __expf(m_run - mx);
    m_run = mx;
    float psum = 0.f;
    unsigned short ph[2][4], plo[2][4];
#pragma unroll
    for (int t = 0; t < 2; ++t)
#pragma unroll
      for (int r = 0; r < 4; ++r) {
        float p = __expf(sc[t][r] - mx);
        psum += p;
        unsigned short hi = f2bf(p);
        ph[t][r] = hi;
        plo[t][r] = f2bf(p - bf2f(hi));
      }
    psum += __shfl_xor(psum, 16);
    psum += __shfl_xor(psum, 32);
    l_run = l_run * corr + psum;
    // ---- rescale O by corr (O lanes: row=q=4g+r; corr lives at lane 4g+r) ----
    float corro[4];
#pragma unroll
    for (int r = 0; r < 4; ++r) corro[r] = __shfl(corr, 4 * g + r);
#pragma unroll
    for (int dt = 0; dt < 8; ++dt)
#pragma unroll
      for (int r = 0; r < 4; ++r) acc[dt][r] *= corro[r];
    // ---- P transpose through LDS: write [q][key], read A-fragments ----
    ushort4 wh, wl;
#pragma unroll
    for (int t = 0; t < 2; ++t) {
      wh.x = ph[t][0]; wh.y = ph[t][1]; wh.z = ph[t][2]; wh.w = ph[t][3];
      wl.x = plo[t][0]; wl.y = plo[t][1]; wl.z = plo[t][2]; wl.w = plo[t][3];
      *(ushort4*)&Pl[wave][0][l15][16 * t + 4 * g] = wh;
      *(ushort4*)&Pl[wave][1][l15][16 * t + 4 * g] = wl;
    }
    short8 pah = *(const short8*)&Pl[wave][0][l15][8 * g];
    short8 pal = *(const short8*)&Pl[wave][1][l15][8 * g];
    // ---- PV: out[q][d] += P[q][k] V[k][d], V^T rows contiguous ----
    size_t vrow = (size_t)(b * 1024 + kvh * 128 + l15) * SEQ + kv0 + 8 * g;
#pragma unroll
    for (int dt = 0; dt < 8; ++dt) {
      short8 vfh = *(const short8*)(vhp + vrow + (size_t)dt * 16 * SEQ);
      short8 vfl = *(const short8*)(vlp + vrow + (size_t)dt * 16 * SEQ);
      acc[dt] = __builtin_amdgcn_mfma_f32_16x16x32_bf16(pah, vfh, acc[dt], 0, 0, 0);
      acc[dt] = __builtin_amdgcn_mfma_f32_16x16x32_bf16(pal, vfh, acc[dt], 0, 0, 0);
      acc[dt] = __builtin_amdgcn_mfma_f32_16x16x32_bf16(pah, vfl, acc[dt], 0, 0, 0);
    }
  }
  // ---- finalize ----
  float linv = 1.f / l_run;
  float lrow[4];
#pragma unroll
  for (int r = 0; r < 4; ++r) lrow[r] = __shfl(linv, 4 * g + r);
#pragma unroll
  for (int r = 0; r < 4; ++r) {
    size_t orow = ((size_t)(b * SEQ + q0 + 4 * g + r) * NHQ + h) * HDD + l15;
#pragma unroll
    for (int dt = 0; dt < 8; ++dt)
      o[orow + dt * 16] = acc[dt][r] * lrow[r];
  }
}

// ---------------------------------------------------------------------------
extern "C" void kernel_launch(void* const* d_in, const int* in_sizes, int n_in,
                              void* d_out, int out_size, void* d_ws, size_t ws_size,
                              hipStream_t stream) {
  const float* x  = (const float*)d_in[0];
  const float* cs = (const float*)d_in[1];
  const float* sn = (const float*)d_in[2];
  const float* wq = (const float*)d_in[3];
  const float* wk = (const float*)d_in[4];
  const float* wv = (const float*)d_in[5];
  const float* wo = (const float*)d_in[6];
  const float* qn = (const float*)d_in[7];
  const float* kn = (const float*)d_in[8];
  float* out = (float*)d_out;
  char* ws = (char*)d_ws;

  // workspace layout (bytes); qb reused as ao, kb reused as aq
  const size_t MB = 1024 * 1024;
  size_t o_xq  = 0;            // 8 MB  bf16 xq
  size_t o_wqt = 8  * MB;      // 8 MB
  size_t o_wkt = 16 * MB;      // 4 MB
  size_t o_wvt = 20 * MB;      // 4 MB
  size_t o_wot = 24 * MB;      // 8 MB
  size_t o_qb  = 32 * MB;      // 16 MB f32 q proj -> later ao
  size_t o_kb  = 48 * MB;      // 8 MB  f32 k proj -> later aq
  size_t o_vth = 56 * MB;      // 4 MB
  size_t o_vtl = 60 * MB;      // 4 MB
  size_t o_qh  = 64 * MB;      // 8 MB
  size_t o_ql  = 72 * MB;      // 8 MB
  size_t o_kh  = 80 * MB;      // 4 MB
  size_t o_kl  = 84 * MB;      // 4 MB
  size_t o_as  = 88 * MB;      // scales etc.
  size_t o_as2 = o_as  + 8192;
  size_t o_prt = o_as2 + 8192;
  size_t o_wsc = o_prt + 8192;

  unsigned short* xq  = (unsigned short*)(ws + o_xq);
  unsigned short* wqt = (unsigned short*)(ws + o_wqt);
  unsigned short* wkt = (unsigned short*)(ws + o_wkt);
  unsigned short* wvt = (unsigned short*)(ws + o_wvt);
  unsigned short* wot = (unsigned short*)(ws + o_wot);
  float* qb  = (float*)(ws + o_qb);
  float* kb  = (float*)(ws + o_kb);
  unsigned short* vth = (unsigned short*)(ws + o_vth);
  unsigned short* vtl = (unsigned short*)(ws + o_vtl);
  unsigned short* qh  = (unsigned short*)(ws + o_qh);
  unsigned short* ql  = (unsigned short*)(ws + o_ql);
  unsigned short* kh  = (unsigned short*)(ws + o_kh);
  unsigned short* kl  = (unsigned short*)(ws + o_kl);
  float* ao = qb;                               // reuse (q f32 dead after normrope)
  unsigned short* aq = (unsigned short*)kb;     // reuse (k f32 dead after normrope)
  float* asx = (float*)(ws + o_as);
  float* as2 = (float*)(ws + o_as2);
  double* prt = (double*)(ws + o_prt);
  float* wsc = (float*)(ws + o_wsc);

  // 1) activation quant of x
  k_actquant<<<TT, 256, 0, stream>>>(x, xq, asx);

  // 2) weight scales
  k_absum<<<256, 256, 0, stream>>>(wq, 2048 * 2048, prt + 0 * 256);
  k_absum<<<256, 256, 0, stream>>>(wk, 1024 * 2048, prt + 1 * 256);
  k_absum<<<256, 256, 0, stream>>>(wv, 1024 * 2048, prt + 2 * 256);
  k_absum<<<256, 256, 0, stream>>>(wo, 2048 * 2048, prt + 3 * 256);
  k_wscale<<<1, 256, 0, stream>>>(prt, wsc);

  // 3) ternary weight quant
  k_wquant<<<512, 256, 0, stream>>>(wq, wqt, wsc + 0, 2048 * 2048);
  k_wquant<<<512, 256, 0, stream>>>(wk, wkt, wsc + 1, 1024 * 2048);
  k_wquant<<<512, 256, 0, stream>>>(wv, wvt, wsc + 2, 1024 * 2048);
  k_wquant<<<512, 256, 0, stream>>>(wo, wot, wsc + 3, 2048 * 2048);

  // 4) projections
  k_gemm_nt<<<dim3(32, 32), 256, 0, stream>>>(xq, wqt, qb, 2048, asx, wsc + 0);
  k_gemm_nt<<<dim3(16, 32), 256, 0, stream>>>(xq, wkt, kb, 1024, asx, wsc + 1);
  k_gemm_vt<<<dim3(32, 16), 256, 0, stream>>>(wvt, xq, vth, vtl, asx, wsc + 2);

  // 5) rmsnorm + rope -> bf16 hi/lo (q gets 1/sqrt(HD))
  k_normrope<<<dim3(TT, NHQ), 128, 0, stream>>>(qb, qn, cs, sn, qh, ql, NHQ, 0.08838834764831845f);
  k_normrope<<<dim3(TT, NKVH), 128, 0, stream>>>(kb, kn, cs, sn, kh, kl, NKVH, 1.0f);

  // 6) MFMA flash attention
  k_attn_mfma<<<dim3(SEQ / 32, 2 * NHQ), 128, 0, stream>>>(qh, ql, kh, kl, vth, vtl, ao);

  // 7) re-quant + output projection
  k_actquant<<<TT, 256, 0, stream>>>(ao, aq, as2);
  k_gemm_nt<<<dim3(32, 32), 256, 0, stream>>>(aq, wot, out, 2048, as2, wsc + 3);
}

// Round 3
// 492.519 us; speedup vs baseline: 2.3691x; 1.4356x over previous
//
#include <hip/hip_runtime.h>
#include <hip/hip_bf16.h>

#define TT   2048   // B*S tokens
#define HH   2048   // hidden dim
#define SEQ  1024
#define NHQ  16
#define NKVH 8
#define HDD  128

typedef __attribute__((ext_vector_type(8))) short short8;
typedef __attribute__((ext_vector_type(4))) float f32x4;

static __device__ __forceinline__ unsigned short f2bf(float f) {
  return (unsigned short)(__float_as_uint(f) >> 16);   // truncate; lo-term compensates
}
static __device__ __forceinline__ float bf2f(unsigned short u) {
  return __uint_as_float(((unsigned int)u) << 16);
}

// global_load_lds with explicit address-space casts
#define GLD_LDS16(gp, lp)                                                        \
  __builtin_amdgcn_global_load_lds(                                              \
      (const __attribute__((address_space(1))) void*)(const void*)(gp),          \
      (__attribute__((address_space(3))) void*)(void*)(lp), 16, 0, 0)

// ---------------------------------------------------------------------------
// K1: per-row act_quant
// ---------------------------------------------------------------------------
__global__ __launch_bounds__(256) void k_actquant(const float* __restrict__ x,
                                                  unsigned short* __restrict__ xq,
                                                  float* __restrict__ as_inv) {
  int row = blockIdx.x;
  const float* xr = x + (size_t)row * HH;
  float amax = 0.f;
  for (int i = threadIdx.x; i < HH; i += 256) amax = fmaxf(amax, fabsf(xr[i]));
  __shared__ float red[256];
  red[threadIdx.x] = amax;
  __syncthreads();
  for (int s = 128; s > 0; s >>= 1) {
    if (threadIdx.x < s) red[threadIdx.x] = fmaxf(red[threadIdx.x], red[threadIdx.x + s]);
    __syncthreads();
  }
  float am = fmaxf(red[0], 1e-5f);
  float scale = 127.f / am;
  if (threadIdx.x == 0) as_inv[row] = am / 127.f;
  unsigned short* xqr = xq + (size_t)row * HH;
  for (int i = threadIdx.x; i < HH; i += 256) {
    float v = rintf(xr[i] * scale);
    v = fminf(fmaxf(v, -128.f), 127.f);
    xqr[i] = f2bf(v);
  }
}

// ---------------------------------------------------------------------------
// K2: deterministic partial |w| sums (f64)
// ---------------------------------------------------------------------------
__global__ __launch_bounds__(256) void k_absum(const float* __restrict__ w, int n,
                                               double* __restrict__ part) {
  double s = 0.0;
  for (int i = blockIdx.x * 256 + threadIdx.x; i < n; i += 256 * 256)
    s += (double)fabsf(w[i]);
  __shared__ double red[256];
  red[threadIdx.x] = s;
  __syncthreads();
  for (int st = 128; st > 0; st >>= 1) {
    if (threadIdx.x < st) red[threadIdx.x] += red[threadIdx.x + st];
    __syncthreads();
  }
  if (threadIdx.x == 0) part[blockIdx.x] = red[0];
}

__global__ __launch_bounds__(256) void k_wscale(const double* __restrict__ part,
                                                float* __restrict__ wsc) {
  __shared__ double red[256];
  const double nvals[4] = {4194304.0, 2097152.0, 2097152.0, 4194304.0};
  for (int w = 0; w < 4; ++w) {
    red[threadIdx.x] = part[w * 256 + threadIdx.x];
    __syncthreads();
    for (int st = 128; st > 0; st >>= 1) {
      if (threadIdx.x < st) red[threadIdx.x] += red[threadIdx.x + st];
      __syncthreads();
    }
    if (threadIdx.x == 0) {
      float mean = (float)(red[0] / nvals[w]);
      wsc[w] = fmaxf(mean, 1e-5f);
    }
    __syncthreads();
  }
}

// ---------------------------------------------------------------------------
// K3: ternary weight quant
// ---------------------------------------------------------------------------
__global__ __launch_bounds__(256) void k_wquant(const float* __restrict__ w,
                                                unsigned short* __restrict__ wt,
                                                const float* __restrict__ wscp, int n) {
  float inv = 1.0f / *wscp;
  for (int i = blockIdx.x * blockDim.x + threadIdx.x; i < n; i += gridDim.x * blockDim.x) {
    float v = rintf(w[i] * inv);
    v = fminf(fmaxf(v, -1.f), 1.f);
    wt[i] = f2bf(v);
  }
}

// ---------------------------------------------------------------------------
// K4: m97-style 128x128 MFMA NT-GEMM, BK=32, global_load_lds staging.
// C[m][n] = sum_k A[m][k]*B[n][k], K=2048.
// mode 0: QK fused epilogue. col<2048 -> dst0 (q f32 [M][2048], scale asx[row]*wscp[0])
//                            col>=2048 -> dst1 (k f32 [M][1024], scale asx[row]*wscp[1])
// mode 1: V epilogue. A=wv rows (features), B=xq rows (tokens). val=acc*asx[col]*wscp[0];
//         hi/lo bf16 to dsth/dstl at ((col>>10)*1024 + row)*1024 + (col&1023)
// mode 2: plain f32: dst0[row*2048+col] = acc*asx[row]*wscp[0]
// ---------------------------------------------------------------------------
__global__ __launch_bounds__(256) void k_gemm128(const unsigned short* __restrict__ A,
                                                 const unsigned short* __restrict__ B,
                                                 int mode,
                                                 float* __restrict__ dst0,
                                                 float* __restrict__ dst1,
                                                 unsigned short* __restrict__ dsth,
                                                 unsigned short* __restrict__ dstl,
                                                 const float* __restrict__ asx,
                                                 const float* __restrict__ wscp) {
  const int K = HH;
  __shared__ unsigned short As[4096];   // [128][32]
  __shared__ unsigned short Bs[4096];
  int wave = threadIdx.x >> 6, lane = threadIdx.x & 63;
  int l15 = lane & 15, g = lane >> 4;
  int wm = wave >> 1, wn = wave & 1;
  int bm = blockIdx.y * 128, bn = blockIdx.x * 128;
  f32x4 acc[4][4] = {};
  int s0 = wave * 64 + lane;

  for (int k0 = 0; k0 < K; k0 += 32) {
    __syncthreads();   // previous iteration's ds_reads complete
#pragma unroll
    for (int r = 0; r < 2; ++r) {
      int s = r * 256 + s0;
      int row = s >> 2, kk = (s & 3) * 8;
      GLD_LDS16(A + (size_t)(bm + row) * K + k0 + kk, As + (size_t)(r * 256 + wave * 64) * 8);
      GLD_LDS16(B + (size_t)(bn + row) * K + k0 + kk, Bs + (size_t)(r * 256 + wave * 64) * 8);
    }
    __syncthreads();   // staging complete (vmcnt drained)
    short8 af[4], bf[4];
#pragma unroll
    for (int i = 0; i < 4; ++i) {
      af[i] = *(const short8*)&As[(wm * 64 + i * 16 + l15) * 32 + g * 8];
      bf[i] = *(const short8*)&Bs[(wn * 64 + i * 16 + l15) * 32 + g * 8];
    }
#pragma unroll
    for (int mi = 0; mi < 4; ++mi)
#pragma unroll
      for (int ni = 0; ni < 4; ++ni)
        acc[mi][ni] = __builtin_amdgcn_mfma_f32_16x16x32_bf16(af[mi], bf[ni], acc[mi][ni], 0, 0, 0);
  }

  float w0 = wscp[0];
  float w1 = (mode == 0) ? wscp[1] : w0;
#pragma unroll
  for (int mi = 0; mi < 4; ++mi) {
#pragma unroll
    for (int rr = 0; rr < 4; ++rr) {
      int crow = bm + wm * 64 + mi * 16 + 4 * g + rr;   // C/D: row=(lane>>4)*4+reg
      if (mode == 0) {
        float rs = asx[crow];
#pragma unroll
        for (int ni = 0; ni < 4; ++ni) {
          int ccol = bn + wn * 64 + ni * 16 + l15;
          float v = acc[mi][ni][rr] * rs;
          if (ccol < 2048) dst0[(size_t)crow * 2048 + ccol] = v * w0;
          else             dst1[(size_t)crow * 1024 + ccol - 2048] = v * w1;
        }
      } else if (mode == 2) {
        float rs = asx[crow] * w0;
#pragma unroll
        for (int ni = 0; ni < 4; ++ni) {
          int ccol = bn + wn * 64 + ni * 16 + l15;
          dst0[(size_t)crow * 2048 + ccol] = acc[mi][ni][rr] * rs;
        }
      } else {   // mode 1: V hi/lo transposed
#pragma unroll
        for (int ni = 0; ni < 4; ++ni) {
          int ccol = bn + wn * 64 + ni * 16 + l15;          // token
          float v = acc[mi][ni][rr] * asx[ccol] * w0;
          unsigned short hi = f2bf(v);
          size_t ad = ((size_t)((ccol >> 10) * 1024 + crow)) * 1024 + (ccol & 1023);
          dsth[ad] = hi;
          dstl[ad] = f2bf(v - bf2f(hi));
        }
      }
    }
  }
}

// ---------------------------------------------------------------------------
// K5: rmsnorm + rope -> bf16 hi/lo arrays (postscale folds 1/sqrt(HD) for q)
// ---------------------------------------------------------------------------
__global__ __launch_bounds__(128) void k_normrope(const float* __restrict__ in,
                                                  const float* __restrict__ nw,
                                                  const float* __restrict__ cs,
                                                  const float* __restrict__ sn,
                                                  unsigned short* __restrict__ oh,
                                                  unsigned short* __restrict__ ol,
                                                  int nh, float postscale) {
  int tok = blockIdx.x, h = blockIdx.y;
  int s = tok & (SEQ - 1);
  const float* row = in + ((size_t)tok * nh + h) * HDD;
  int d = threadIdx.x;
  float v = row[d];
  __shared__ float red[128];
  red[d] = v * v;
  __syncthreads();
  for (int st = 64; st > 0; st >>= 1) {
    if (d < st) red[d] += red[d + st];
    __syncthreads();
  }
  float inv = rsqrtf(red[0] / 128.f + 1e-6f);
  float nv = nw[d] * (v * inv);
  int od = (d < 64) ? d + 64 : d - 64;
  float o = nw[od] * (row[od] * inv);
  float rh = (d < 64) ? -o : o;
  float res = (nv * cs[s * HDD + d] + rh * sn[s * HDD + d]) * postscale;
  size_t oi = ((size_t)tok * nh + h) * HDD + d;
  unsigned short hi = f2bf(res);
  oh[oi] = hi;
  ol[oi] = f2bf(res - bf2f(hi));
}

// ---------------------------------------------------------------------------
// K6: MFMA flash attention with issue-early loads.
// 2 waves/block, 16 q each. Swapped QK^T, hi/lo splits on Q,K,P,V.
// V loads issued at loop top (consumed post-softmax); K regs reloaded for kv+1
// right after QK MFMAs (in flight across softmax + P-LDS + PV).
// ---------------------------------------------------------------------------
__global__ __launch_bounds__(128) void k_attn_mfma(const unsigned short* __restrict__ qhp,
                                                   const unsigned short* __restrict__ qlp,
                                                   const unsigned short* __restrict__ khp,
                                                   const unsigned short* __restrict__ klp,
                                                   const unsigned short* __restrict__ vhp,
                                                   const unsigned short* __restrict__ vlp,
                                                   float* __restrict__ o) {
  int qt = gridDim.x - 1 - blockIdx.x;       // heavy blocks dispatch first
  int bh = blockIdx.y;
  int b = bh >> 4, h = bh & 15, kvh = h >> 1;
  int wave = threadIdx.x >> 6, lane = threadIdx.x & 63;
  int l15 = lane & 15, g = lane >> 4;
  int q0 = qt * 32 + wave * 16;
  int qglob = q0 + l15;

  __shared__ unsigned short Pl[2][2][16][40];  // [wave][hi/lo][q][key pad->40]

  short8 qfh[4], qfl[4];
  {
    const unsigned short* qb = qhp + ((size_t)(b * SEQ + qglob) * NHQ + h) * HDD + g * 8;
    const unsigned short* ql = qlp + ((size_t)(b * SEQ + qglob) * NHQ + h) * HDD + g * 8;
#pragma unroll
    for (int c = 0; c < 4; ++c) {
      qfh[c] = *(const short8*)(qb + c * 32);
      qfl[c] = *(const short8*)(ql + c * 32);
    }
  }

  short8 kfh[2][4], kfl[2][4];
#define LOADK(KV0)                                                                          \
  {                                                                                         \
    _Pragma("unroll")                                                                       \
    for (int t = 0; t < 2; ++t) {                                                           \
      size_t koff = ((size_t)(b * SEQ + (KV0) + 16 * t + l15) * NKVH + kvh) * HDD + g * 8;  \
      const unsigned short* kbh = khp + koff;                                               \
      const unsigned short* kbl = klp + koff;                                               \
      _Pragma("unroll")                                                                     \
      for (int c = 0; c < 4; ++c) {                                                         \
        kfh[t][c] = *(const short8*)(kbh + c * 32);                                         \
        kfl[t][c] = *(const short8*)(kbl + c * 32);                                         \
      }                                                                                     \
    }                                                                                       \
  }

  f32x4 acc[8] = {};
  float m_run = -INFINITY, l_run = 0.f;
  int nkv = q0 / 32 + 1;
  LOADK(0);

  for (int kv = 0; kv < nkv; ++kv) {
    int kv0 = kv * 32;
    // ---- V loads for THIS iteration, issued early (used only after softmax) ----
    short8 vfh[8], vfl[8];
    size_t vrow = (size_t)(b * 1024 + kvh * 128 + l15) * SEQ + kv0 + 8 * g;
#pragma unroll
    for (int dt = 0; dt < 8; ++dt) {
      vfh[dt] = *(const short8*)(vhp + vrow + (size_t)dt * 16 * SEQ);
      vfl[dt] = *(const short8*)(vlp + vrow + (size_t)dt * 16 * SEQ);
    }
    // ---- QK^T from preloaded K regs ----
    float sc[2][4];
#pragma unroll
    for (int t = 0; t < 2; ++t) {
      f32x4 s = {0.f, 0.f, 0.f, 0.f};
#pragma unroll
      for (int c = 0; c < 4; ++c) {
        s = __builtin_amdgcn_mfma_f32_16x16x32_bf16(kfh[t][c], qfh[c], s, 0, 0, 0);
        s = __builtin_amdgcn_mfma_f32_16x16x32_bf16(kfl[t][c], qfh[c], s, 0, 0, 0);
        s = __builtin_amdgcn_mfma_f32_16x16x32_bf16(kfh[t][c], qfl[c], s, 0, 0, 0);
      }
#pragma unroll
      for (int r = 0; r < 4; ++r) sc[t][r] = s[r];
    }
    // ---- prefetch next K into same regs (dead after QK; hides under softmax+PV) ----
    if (kv + 1 < nkv) LOADK(kv0 + 32);
    // ---- causal mask ----
    if (kv == nkv - 1) {
#pragma unroll
      for (int t = 0; t < 2; ++t)
#pragma unroll
        for (int r = 0; r < 4; ++r)
          if (kv0 + 16 * t + 4 * g + r > qglob) sc[t][r] = -INFINITY;
    }
    // ---- online softmax (lane owns query l15) ----
    float mx = m_run;
#pragma unroll
    for (int t = 0; t < 2; ++t)
#pragma unroll
      for (int r = 0; r < 4; ++r) mx = fmaxf(mx, sc[t][r]);
    mx = fmaxf(mx, __shfl_xor(mx, 16));
    mx = fmaxf(mx, __shfl_xor(mx, 32));
    float corr = __expf(m_run - mx);
    m_run = mx;
    float psum = 0.f;
    unsigned short ph[2][4], plo[2][4];
#pragma unroll
    for (int t = 0; t < 2; ++t)
#pragma unroll
      for (int r = 0; r < 4; ++r) {
        float p = __expf(sc[t][r] - mx);
        psum += p;
        unsigned short hi = f2bf(p);
        ph[t][r] = hi;
        plo[t][r] = f2bf(p - bf2f(hi));
      }
    psum += __shfl_xor(psum, 16);
    psum += __shfl_xor(psum, 32);
    l_run = l_run * corr + psum;
    // ---- rescale O ----
    float corro[4];
#pragma unroll
    for (int r = 0; r < 4; ++r) corro[r] = __shfl(corr, 4 * g + r);
#pragma unroll
    for (int dt = 0; dt < 8; ++dt)
#pragma unroll
      for (int r = 0; r < 4; ++r) acc[dt][r] *= corro[r];
    // ---- P transpose through LDS ----
    ushort4 wh, wl;
#pragma unroll
    for (int t = 0; t < 2; ++t) {
      wh.x = ph[t][0]; wh.y = ph[t][1]; wh.z = ph[t][2]; wh.w = ph[t][3];
      wl.x = plo[t][0]; wl.y = plo[t][1]; wl.z = plo[t][2]; wl.w = plo[t][3];
      *(ushort4*)&Pl[wave][0][l15][16 * t + 4 * g] = wh;
      *(ushort4*)&Pl[wave][1][l15][16 * t + 4 * g] = wl;
    }
    short8 pah = *(const short8*)&Pl[wave][0][l15][8 * g];
    short8 pal = *(const short8*)&Pl[wave][1][l15][8 * g];
    // ---- PV from preloaded V regs ----
#pragma unroll
    for (int dt = 0; dt < 8; ++dt) {
      acc[dt] = __builtin_amdgcn_mfma_f32_16x16x32_bf16(pah, vfh[dt], acc[dt], 0, 0, 0);
      acc[dt] = __builtin_amdgcn_mfma_f32_16x16x32_bf16(pal, vfh[dt], acc[dt], 0, 0, 0);
      acc[dt] = __builtin_amdgcn_mfma_f32_16x16x32_bf16(pah, vfl[dt], acc[dt], 0, 0, 0);
    }
  }
  // ---- finalize ----
  float linv = 1.f / l_run;
  float lrow[4];
#pragma unroll
  for (int r = 0; r < 4; ++r) lrow[r] = __shfl(linv, 4 * g + r);
#pragma unroll
  for (int r = 0; r < 4; ++r) {
    size_t orow = ((size_t)(b * SEQ + q0 + 4 * g + r) * NHQ + h) * HDD + l15;
#pragma unroll
    for (int dt = 0; dt < 8; ++dt)
      o[orow + dt * 16] = acc[dt][r] * lrow[r];
  }
#undef LOADK
}

// ---------------------------------------------------------------------------
extern "C" void kernel_launch(void* const* d_in, const int* in_sizes, int n_in,
                              void* d_out, int out_size, void* d_ws, size_t ws_size,
                              hipStream_t stream) {
  const float* x  = (const float*)d_in[0];
  const float* cs = (const float*)d_in[1];
  const float* sn = (const float*)d_in[2];
  const float* wq = (const float*)d_in[3];
  const float* wk = (const float*)d_in[4];
  const float* wv = (const float*)d_in[5];
  const float* wo = (const float*)d_in[6];
  const float* qn = (const float*)d_in[7];
  const float* kn = (const float*)d_in[8];
  float* out = (float*)d_out;
  char* ws = (char*)d_ws;

  const size_t MB = 1024 * 1024;
  size_t o_xq  = 0;            // 8 MB  bf16 xq
  size_t o_wqk = 8  * MB;      // 12 MB [3072][2048] bf16 (wq rows 0..2047, wk rows 2048..3071)
  size_t o_wvt = 20 * MB;      // 4 MB
  size_t o_wot = 24 * MB;      // 8 MB
  size_t o_qb  = 32 * MB;      // 16 MB f32 q proj -> later ao
  size_t o_kb  = 48 * MB;      // 8 MB  f32 k proj -> later aq
  size_t o_vth = 56 * MB;      // 4 MB
  size_t o_vtl = 60 * MB;      // 4 MB
  size_t o_qh  = 64 * MB;      // 8 MB
  size_t o_ql  = 72 * MB;      // 8 MB
  size_t o_kh  = 80 * MB;      // 4 MB
  size_t o_kl  = 84 * MB;      // 4 MB
  size_t o_as  = 88 * MB;
  size_t o_as2 = o_as  + 8192;
  size_t o_prt = o_as2 + 8192;
  size_t o_wsc = o_prt + 8192;

  unsigned short* xq  = (unsigned short*)(ws + o_xq);
  unsigned short* wqk = (unsigned short*)(ws + o_wqk);
  unsigned short* wvt = (unsigned short*)(ws + o_wvt);
  unsigned short* wot = (unsigned short*)(ws + o_wot);
  float* qb  = (float*)(ws + o_qb);
  float* kb  = (float*)(ws + o_kb);
  unsigned short* vth = (unsigned short*)(ws + o_vth);
  unsigned short* vtl = (unsigned short*)(ws + o_vtl);
  unsigned short* qh  = (unsigned short*)(ws + o_qh);
  unsigned short* ql  = (unsigned short*)(ws + o_ql);
  unsigned short* kh  = (unsigned short*)(ws + o_kh);
  unsigned short* kl  = (unsigned short*)(ws + o_kl);
  float* ao = qb;                               // reuse (q f32 dead after normrope)
  unsigned short* aq = (unsigned short*)kb;     // reuse (k f32 dead after normrope)
  float* asx = (float*)(ws + o_as);
  float* as2 = (float*)(ws + o_as2);
  double* prt = (double*)(ws + o_prt);
  float* wsc = (float*)(ws + o_wsc);

  // 1) activation quant of x
  k_actquant<<<TT, 256, 0, stream>>>(x, xq, asx);

  // 2) weight scales
  k_absum<<<256, 256, 0, stream>>>(wq, 2048 * 2048, prt + 0 * 256);
  k_absum<<<256, 256, 0, stream>>>(wk, 1024 * 2048, prt + 1 * 256);
  k_absum<<<256, 256, 0, stream>>>(wv, 1024 * 2048, prt + 2 * 256);
  k_absum<<<256, 256, 0, stream>>>(wo, 2048 * 2048, prt + 3 * 256);
  k_wscale<<<1, 256, 0, stream>>>(prt, wsc);

  // 3) ternary weight quant (wq+wk into one [3072][2048] buffer)
  k_wquant<<<512, 256, 0, stream>>>(wq, wqk, wsc + 0, 2048 * 2048);
  k_wquant<<<512, 256, 0, stream>>>(wk, wqk + 2048 * 2048, wsc + 1, 1024 * 2048);
  k_wquant<<<512, 256, 0, stream>>>(wv, wvt, wsc + 2, 1024 * 2048);
  k_wquant<<<512, 256, 0, stream>>>(wo, wot, wsc + 3, 2048 * 2048);

  // 4) projections (m97-style LDS-staged MFMA GEMM)
  // QK fused: A=xq [2048], B=wqk [3072] -> grid (3072/128, 2048/128)
  k_gemm128<<<dim3(24, 16), 256, 0, stream>>>(xq, wqk, 0, qb, kb, nullptr, nullptr, asx, wsc);
  // V: A=wvt [1024 features], B=xq [2048 tokens] -> hi/lo transposed out
  k_gemm128<<<dim3(16, 8), 256, 0, stream>>>(wvt, xq, 1, nullptr, nullptr, vth, vtl, asx, wsc + 2);

  // 5) rmsnorm + rope -> bf16 hi/lo (q gets 1/sqrt(HD))
  k_normrope<<<dim3(TT, NHQ), 128, 0, stream>>>(qb, qn, cs, sn, qh, ql, NHQ, 0.08838834764831845f);
  k_normrope<<<dim3(TT, NKVH), 128, 0, stream>>>(kb, kn, cs, sn, kh, kl, NKVH, 1.0f);

  // 6) MFMA flash attention
  k_attn_mfma<<<dim3(SEQ / 32, 2 * NHQ), 128, 0, stream>>>(qh, ql, kh, kl, vth, vtl, ao);

  // 7) re-quant + output projection
  k_actquant<<<TT, 256, 0, stream>>>(ao, aq, as2);
  k_gemm128<<<dim3(16, 16), 256, 0, stream>>>(aq, wot, 2, out, nullptr, nullptr, nullptr, as2, wsc + 3);
}

// Round 4
// 337.403 us; speedup vs baseline: 3.4583x; 1.4597x over previous
//
#include <hip/hip_runtime.h>
#include <hip/hip_bf16.h>

#define TT   2048   // B*S tokens
#define HH   2048   // hidden dim
#define SEQ  1024
#define NHQ  16
#define NKVH 8
#define HDD  128

typedef __attribute__((ext_vector_type(8))) short short8;
typedef __attribute__((ext_vector_type(4))) float f32x4;

static __device__ __forceinline__ unsigned short f2bf(float f) {
  return (unsigned short)(__float_as_uint(f) >> 16);   // truncate; lo-term compensates
}
static __device__ __forceinline__ float bf2f(unsigned short u) {
  return __uint_as_float(((unsigned int)u) << 16);
}

// global_load_lds with explicit address-space casts
#define GLD_LDS16(gp, lp)                                                        \
  __builtin_amdgcn_global_load_lds(                                              \
      (const __attribute__((address_space(1))) void*)(const void*)(gp),          \
      (__attribute__((address_space(3))) void*)(void*)(lp), 16, 0, 0)

// ---------------------------------------------------------------------------
// K1: per-row act_quant
// ---------------------------------------------------------------------------
__global__ __launch_bounds__(256) void k_actquant(const float* __restrict__ x,
                                                  unsigned short* __restrict__ xq,
                                                  float* __restrict__ as_inv) {
  int row = blockIdx.x;
  const float* xr = x + (size_t)row * HH;
  float amax = 0.f;
  for (int i = threadIdx.x; i < HH; i += 256) amax = fmaxf(amax, fabsf(xr[i]));
  __shared__ float red[256];
  red[threadIdx.x] = amax;
  __syncthreads();
  for (int s = 128; s > 0; s >>= 1) {
    if (threadIdx.x < s) red[threadIdx.x] = fmaxf(red[threadIdx.x], red[threadIdx.x + s]);
    __syncthreads();
  }
  float am = fmaxf(red[0], 1e-5f);
  float scale = 127.f / am;
  if (threadIdx.x == 0) as_inv[row] = am / 127.f;
  unsigned short* xqr = xq + (size_t)row * HH;
  for (int i = threadIdx.x; i < HH; i += 256) {
    float v = rintf(xr[i] * scale);
    v = fminf(fmaxf(v, -128.f), 127.f);
    xqr[i] = f2bf(v);
  }
}

// ---------------------------------------------------------------------------
// K2: deterministic partial |w| sums (f64)
// ---------------------------------------------------------------------------
__global__ __launch_bounds__(256) void k_absum(const float* __restrict__ w, int n,
                                               double* __restrict__ part) {
  double s = 0.0;
  for (int i = blockIdx.x * 256 + threadIdx.x; i < n; i += 256 * 256)
    s += (double)fabsf(w[i]);
  __shared__ double red[256];
  red[threadIdx.x] = s;
  __syncthreads();
  for (int st = 128; st > 0; st >>= 1) {
    if (threadIdx.x < st) red[threadIdx.x] += red[threadIdx.x + st];
    __syncthreads();
  }
  if (threadIdx.x == 0) part[blockIdx.x] = red[0];
}

__global__ __launch_bounds__(256) void k_wscale(const double* __restrict__ part,
                                                float* __restrict__ wsc) {
  __shared__ double red[256];
  const double nvals[4] = {4194304.0, 2097152.0, 2097152.0, 4194304.0};
  for (int w = 0; w < 4; ++w) {
    red[threadIdx.x] = part[w * 256 + threadIdx.x];
    __syncthreads();
    for (int st = 128; st > 0; st >>= 1) {
      if (threadIdx.x < st) red[threadIdx.x] += red[threadIdx.x + st];
      __syncthreads();
    }
    if (threadIdx.x == 0) {
      float mean = (float)(red[0] / nvals[w]);
      wsc[w] = fmaxf(mean, 1e-5f);
    }
    __syncthreads();
  }
}

// ---------------------------------------------------------------------------
// K3: ternary weight quant
// ---------------------------------------------------------------------------
__global__ __launch_bounds__(256) void k_wquant(const float* __restrict__ w,
                                                unsigned short* __restrict__ wt,
                                                const float* __restrict__ wscp, int n) {
  float inv = 1.0f / *wscp;
  for (int i = blockIdx.x * blockDim.x + threadIdx.x; i < n; i += gridDim.x * blockDim.x) {
    float v = rintf(w[i] * inv);
    v = fminf(fmaxf(v, -1.f), 1.f);
    wt[i] = f2bf(v);
  }
}

// ---------------------------------------------------------------------------
// K4: m97-style 128x128 MFMA NT-GEMM, BK=32, global_load_lds staging.
// ---------------------------------------------------------------------------
__global__ __launch_bounds__(256) void k_gemm128(const unsigned short* __restrict__ A,
                                                 const unsigned short* __restrict__ B,
                                                 int mode,
                                                 float* __restrict__ dst0,
                                                 float* __restrict__ dst1,
                                                 unsigned short* __restrict__ dsth,
                                                 unsigned short* __restrict__ dstl,
                                                 const float* __restrict__ asx,
                                                 const float* __restrict__ wscp) {
  const int K = HH;
  __shared__ unsigned short As[4096];   // [128][32]
  __shared__ unsigned short Bs[4096];
  int wave = threadIdx.x >> 6, lane = threadIdx.x & 63;
  int l15 = lane & 15, g = lane >> 4;
  int wm = wave >> 1, wn = wave & 1;
  int bm = blockIdx.y * 128, bn = blockIdx.x * 128;
  f32x4 acc[4][4] = {};
  int s0 = wave * 64 + lane;

  for (int k0 = 0; k0 < K; k0 += 32) {
    __syncthreads();
#pragma unroll
    for (int r = 0; r < 2; ++r) {
      int s = r * 256 + s0;
      int row = s >> 2, kk = (s & 3) * 8;
      GLD_LDS16(A + (size_t)(bm + row) * K + k0 + kk, As + (size_t)(r * 256 + wave * 64) * 8);
      GLD_LDS16(B + (size_t)(bn + row) * K + k0 + kk, Bs + (size_t)(r * 256 + wave * 64) * 8);
    }
    __syncthreads();
    short8 af[4], bf[4];
#pragma unroll
    for (int i = 0; i < 4; ++i) {
      af[i] = *(const short8*)&As[(wm * 64 + i * 16 + l15) * 32 + g * 8];
      bf[i] = *(const short8*)&Bs[(wn * 64 + i * 16 + l15) * 32 + g * 8];
    }
#pragma unroll
    for (int mi = 0; mi < 4; ++mi)
#pragma unroll
      for (int ni = 0; ni < 4; ++ni)
        acc[mi][ni] = __builtin_amdgcn_mfma_f32_16x16x32_bf16(af[mi], bf[ni], acc[mi][ni], 0, 0, 0);
  }

  float w0 = wscp[0];
  float w1 = (mode == 0) ? wscp[1] : w0;
#pragma unroll
  for (int mi = 0; mi < 4; ++mi) {
#pragma unroll
    for (int rr = 0; rr < 4; ++rr) {
      int crow = bm + wm * 64 + mi * 16 + 4 * g + rr;
      if (mode == 0) {
        float rs = asx[crow];
#pragma unroll
        for (int ni = 0; ni < 4; ++ni) {
          int ccol = bn + wn * 64 + ni * 16 + l15;
          float v = acc[mi][ni][rr] * rs;
          if (ccol < 2048) dst0[(size_t)crow * 2048 + ccol] = v * w0;
          else             dst1[(size_t)crow * 1024 + ccol - 2048] = v * w1;
        }
      } else if (mode == 2) {
        float rs = asx[crow] * w0;
#pragma unroll
        for (int ni = 0; ni < 4; ++ni) {
          int ccol = bn + wn * 64 + ni * 16 + l15;
          dst0[(size_t)crow * 2048 + ccol] = acc[mi][ni][rr] * rs;
        }
      } else {   // mode 1: V hi/lo transposed
#pragma unroll
        for (int ni = 0; ni < 4; ++ni) {
          int ccol = bn + wn * 64 + ni * 16 + l15;
          float v = acc[mi][ni][rr] * asx[ccol] * w0;
          unsigned short hi = f2bf(v);
          size_t ad = ((size_t)((ccol >> 10) * 1024 + crow)) * 1024 + (ccol & 1023);
          dsth[ad] = hi;
          dstl[ad] = f2bf(v - bf2f(hi));
        }
      }
    }
  }
}

// ---------------------------------------------------------------------------
// K5: rmsnorm + rope -> bf16 hi/lo arrays
// ---------------------------------------------------------------------------
__global__ __launch_bounds__(128) void k_normrope(const float* __restrict__ in,
                                                  const float* __restrict__ nw,
                                                  const float* __restrict__ cs,
                                                  const float* __restrict__ sn,
                                                  unsigned short* __restrict__ oh,
                                                  unsigned short* __restrict__ ol,
                                                  int nh, float postscale) {
  int tok = blockIdx.x, h = blockIdx.y;
  int s = tok & (SEQ - 1);
  const float* row = in + ((size_t)tok * nh + h) * HDD;
  int d = threadIdx.x;
  float v = row[d];
  __shared__ float red[128];
  red[d] = v * v;
  __syncthreads();
  for (int st = 64; st > 0; st >>= 1) {
    if (d < st) red[d] += red[d + st];
    __syncthreads();
  }
  float inv = rsqrtf(red[0] / 128.f + 1e-6f);
  float nv = nw[d] * (v * inv);
  int od = (d < 64) ? d + 64 : d - 64;
  float o = nw[od] * (row[od] * inv);
  float rh = (d < 64) ? -o : o;
  float res = (nv * cs[s * HDD + d] + rh * sn[s * HDD + d]) * postscale;
  size_t oi = ((size_t)tok * nh + h) * HDD + d;
  unsigned short hi = f2bf(res);
  oh[oi] = hi;
  ol[oi] = f2bf(res - bf2f(hi));
}

// ---------------------------------------------------------------------------
// K6: MFMA flash attention, 4 waves/block, Q-tile 64 (16 q/wave), KV tile 32.
// K/V hi/lo staged to LDS via global_load_lds (double-buffered, 2-phase),
// XOR-swizzled on the GLOBAL SOURCE side (LDS written linearly; reads apply
// the same XOR). Swapped QK^T; hi/lo error-compensated MFMA on Q,K,P,V.
// ---------------------------------------------------------------------------
__global__ __launch_bounds__(256) void k_attn_mfma(const unsigned short* __restrict__ qhp,
                                                   const unsigned short* __restrict__ qlp,
                                                   const unsigned short* __restrict__ khp,
                                                   const unsigned short* __restrict__ klp,
                                                   const unsigned short* __restrict__ vhp,
                                                   const unsigned short* __restrict__ vlp,
                                                   float* __restrict__ o) {
  // ---- work remap: XCD-chunked (same bh -> same XCD L2) + zigzag qt ----
  int i = blockIdx.x + blockIdx.y * 16;          // 512 blocks
  int w = (i & 7) * 64 + (i >> 3);               // bijective, 8 XCD chunks of 64
  int y = w >> 4;                                // bh
  int widx = w & 15;
  int qt = (widx & 1) ? (widx >> 1) : (15 - (widx >> 1));  // zigzag heavy/light
  int b = y >> 4, h = y & 15, kvh = h >> 1;
  int wave = threadIdx.x >> 6, lane = threadIdx.x & 63;
  int l15 = lane & 15, g = lane >> 4;
  int q0b = qt * 64;
  int q0w = q0b + wave * 16;
  int qglob = q0w + l15;

  __shared__ unsigned short Kh[2][4096], Kl[2][4096];   // [buf][ki*128+d] swizzled
  __shared__ unsigned short Vh[2][4096], Vl[2][4096];   // [buf][d*32+s]   swizzled
  __shared__ unsigned short Plds[4][2][16][40];

  // Q fragments (B-operand): lane holds Q[q=l15][c*32 + g*8 + j]
  short8 qfh[4], qfl[4];
  {
    const unsigned short* qb = qhp + ((size_t)(b * SEQ + qglob) * NHQ + h) * HDD + g * 8;
    const unsigned short* ql = qlp + ((size_t)(b * SEQ + qglob) * NHQ + h) * HDD + g * 8;
#pragma unroll
    for (int c = 0; c < 4; ++c) {
      qfh[c] = *(const short8*)(qb + c * 32);
      qfl[c] = *(const short8*)(ql + c * 32);
    }
  }

  // stage KV tile (32 keys) into buffer BFN. 8 chunks of 16B per thread.
  // K rows: 256B, source pre-swizzled by ((ki&7)<<4); V rows: 64B, ((d&3)<<4).
#define STAGE(KV0N, BFN)                                                              \
  {                                                                                   \
    int c0 = wave * 64 + lane;                                                        \
    _Pragma("unroll")                                                                 \
    for (int tch = 0; tch < 2; ++tch) {                                               \
      int c = tch * 256 + c0;                                                         \
      int ki = c >> 4, j = (c & 15) << 4;                                             \
      int js = j ^ ((ki & 7) << 4);                                                   \
      size_t kbase = ((size_t)(b * SEQ + (KV0N) + ki) * NKVH + kvh) * HDD;            \
      GLD_LDS16((const char*)(khp + kbase) + js, &Kh[BFN][c * 8]);                    \
      GLD_LDS16((const char*)(klp + kbase) + js, &Kl[BFN][c * 8]);                    \
      int d = c >> 2, jv = (c & 3) << 4;                                              \
      int jvs = jv ^ ((d & 3) << 4);                                                  \
      size_t vbase = ((size_t)(b * 1024 + kvh * 128 + d)) * SEQ + (KV0N);             \
      GLD_LDS16((const char*)(vhp + vbase) + jvs, &Vh[BFN][c * 8]);                   \
      GLD_LDS16((const char*)(vlp + vbase) + jvs, &Vl[BFN][c * 8]);                   \
    }                                                                                 \
  }

  f32x4 acc[8] = {};
  float m_run = -INFINITY, l_run = 0.f;
  int nkv = 2 * qt + 2;                      // block-level KV tiles

  STAGE(0, 0);
  __syncthreads();

  int bf = 0;
  for (int kv = 0; kv < nkv; ++kv) {
    int kv0 = kv * 32;
    if (kv + 1 < nkv) STAGE(kv0 + 32, bf ^ 1);
    bool active = (kv0 <= q0w + 15);         // wave-uniform: skip fully-masked tiles
    if (active) {
      // ---- QK^T from LDS K (swizzled reads, 2-way conflict) ----
      float sc[2][4];
#pragma unroll
      for (int t = 0; t < 2; ++t) {
        int row = 16 * t + l15;
        int rbyte = row * 256, sw = (row & 7) << 4;
        f32x4 s = {0.f, 0.f, 0.f, 0.f};
#pragma unroll
        for (int c = 0; c < 4; ++c) {
          int off = rbyte + ((c * 64 + g * 16) ^ sw);
          short8 kfh = *(const short8*)((const char*)&Kh[bf][0] + off);
          short8 kfl = *(const short8*)((const char*)&Kl[bf][0] + off);
          s = __builtin_amdgcn_mfma_f32_16x16x32_bf16(kfh, qfh[c], s, 0, 0, 0);
          s = __builtin_amdgcn_mfma_f32_16x16x32_bf16(kfl, qfh[c], s, 0, 0, 0);
          s = __builtin_amdgcn_mfma_f32_16x16x32_bf16(kfh, qfl[c], s, 0, 0, 0);
        }
#pragma unroll
        for (int r = 0; r < 4; ++r) sc[t][r] = s[r];
      }
      // ---- causal mask ----
      if (kv0 + 31 > q0w) {
#pragma unroll
        for (int t = 0; t < 2; ++t)
#pragma unroll
          for (int r = 0; r < 4; ++r)
            if (kv0 + 16 * t + 4 * g + r > qglob) sc[t][r] = -INFINITY;
      }
      // ---- online softmax (lane owns query l15) ----
      float mx = m_run;
#pragma unroll
      for (int t = 0; t < 2; ++t)
#pragma unroll
        for (int r = 0; r < 4; ++r) mx = fmaxf(mx, sc[t][r]);
      mx = fmaxf(mx, __shfl_xor(mx, 16));
      mx = fmaxf(mx, __shfl_xor(mx, 32));
      float corr = __expf(m_run - mx);
      m_run = mx;
      float psum = 0.f;
      unsigned short ph[2][4], plo[2][4];
#pragma unroll
      for (int t = 0; t < 2; ++t)
#pragma unroll
        for (int r = 0; r < 4; ++r) {
          float p = __expf(sc[t][r] - mx);
          psum += p;
          unsigned short hi = f2bf(p);
          ph[t][r] = hi;
          plo[t][r] = f2bf(p - bf2f(hi));
        }
      psum += __shfl_xor(psum, 16);
      psum += __shfl_xor(psum, 32);
      l_run = l_run * corr + psum;
      // ---- rescale O ----
      float corro[4];
#pragma unroll
      for (int r = 0; r < 4; ++r) corro[r] = __shfl(corr, 4 * g + r);
#pragma unroll
      for (int dt = 0; dt < 8; ++dt)
#pragma unroll
        for (int r = 0; r < 4; ++r) acc[dt][r] *= corro[r];
      // ---- P transpose through per-wave LDS ----
      ushort4 wh, wl;
#pragma unroll
      for (int t = 0; t < 2; ++t) {
        wh.x = ph[t][0]; wh.y = ph[t][1]; wh.z = ph[t][2]; wh.w = ph[t][3];
        wl.x = plo[t][0]; wl.y = plo[t][1]; wl.z = plo[t][2]; wl.w = plo[t][3];
        *(ushort4*)&Plds[wave][0][l15][16 * t + 4 * g] = wh;
        *(ushort4*)&Plds[wave][1][l15][16 * t + 4 * g] = wl;
      }
      short8 pah = *(const short8*)&Plds[wave][0][l15][8 * g];
      short8 pal = *(const short8*)&Plds[wave][1][l15][8 * g];
      // ---- PV from LDS V^T (swizzled reads) ----
#pragma unroll
      for (int dt = 0; dt < 8; ++dt) {
        int d = dt * 16 + l15;
        int off = d * 64 + ((g * 16) ^ ((d & 3) << 4));
        short8 vfh = *(const short8*)((const char*)&Vh[bf][0] + off);
        short8 vfl = *(const short8*)((const char*)&Vl[bf][0] + off);
        acc[dt] = __builtin_amdgcn_mfma_f32_16x16x32_bf16(pah, vfh, acc[dt], 0, 0, 0);
        acc[dt] = __builtin_amdgcn_mfma_f32_16x16x32_bf16(pal, vfh, acc[dt], 0, 0, 0);
        acc[dt] = __builtin_amdgcn_mfma_f32_16x16x32_bf16(pah, vfl, acc[dt], 0, 0, 0);
      }
    }
    __syncthreads();   // staging of next buf done + all waves done reading bf
    bf ^= 1;
  }
#undef STAGE

  // ---- finalize ----
  float linv = 1.f / l_run;
  float lrow[4];
#pragma unroll
  for (int r = 0; r < 4; ++r) lrow[r] = __shfl(linv, 4 * g + r);
#pragma unroll
  for (int r = 0; r < 4; ++r) {
    size_t orow = ((size_t)(b * SEQ + q0w + 4 * g + r) * NHQ + h) * HDD + l15;
#pragma unroll
    for (int dt = 0; dt < 8; ++dt)
      o[orow + dt * 16] = acc[dt][r] * lrow[r];
  }
}

// ---------------------------------------------------------------------------
extern "C" void kernel_launch(void* const* d_in, const int* in_sizes, int n_in,
                              void* d_out, int out_size, void* d_ws, size_t ws_size,
                              hipStream_t stream) {
  const float* x  = (const float*)d_in[0];
  const float* cs = (const float*)d_in[1];
  const float* sn = (const float*)d_in[2];
  const float* wq = (const float*)d_in[3];
  const float* wk = (const float*)d_in[4];
  const float* wv = (const float*)d_in[5];
  const float* wo = (const float*)d_in[6];
  const float* qn = (const float*)d_in[7];
  const float* kn = (const float*)d_in[8];
  float* out = (float*)d_out;
  char* ws = (char*)d_ws;

  const size_t MB = 1024 * 1024;
  size_t o_xq  = 0;            // 8 MB  bf16 xq
  size_t o_wqk = 8  * MB;      // 12 MB [3072][2048] bf16
  size_t o_wvt = 20 * MB;      // 4 MB
  size_t o_wot = 24 * MB;      // 8 MB
  size_t o_qb  = 32 * MB;      // 16 MB f32 q proj -> later ao
  size_t o_kb  = 48 * MB;      // 8 MB  f32 k proj -> later aq
  size_t o_vth = 56 * MB;      // 4 MB
  size_t o_vtl = 60 * MB;      // 4 MB
  size_t o_qh  = 64 * MB;      // 8 MB
  size_t o_ql  = 72 * MB;      // 8 MB
  size_t o_kh  = 80 * MB;      // 4 MB
  size_t o_kl  = 84 * MB;      // 4 MB
  size_t o_as  = 88 * MB;
  size_t o_as2 = o_as  + 8192;
  size_t o_prt = o_as2 + 8192;
  size_t o_wsc = o_prt + 8192;

  unsigned short* xq  = (unsigned short*)(ws + o_xq);
  unsigned short* wqk = (unsigned short*)(ws + o_wqk);
  unsigned short* wvt = (unsigned short*)(ws + o_wvt);
  unsigned short* wot = (unsigned short*)(ws + o_wot);
  float* qb  = (float*)(ws + o_qb);
  float* kb  = (float*)(ws + o_kb);
  unsigned short* vth = (unsigned short*)(ws + o_vth);
  unsigned short* vtl = (unsigned short*)(ws + o_vtl);
  unsigned short* qh  = (unsigned short*)(ws + o_qh);
  unsigned short* ql  = (unsigned short*)(ws + o_ql);
  unsigned short* kh  = (unsigned short*)(ws + o_kh);
  unsigned short* kl  = (unsigned short*)(ws + o_kl);
  float* ao = qb;
  unsigned short* aq = (unsigned short*)kb;
  float* asx = (float*)(ws + o_as);
  float* as2 = (float*)(ws + o_as2);
  double* prt = (double*)(ws + o_prt);
  float* wsc = (float*)(ws + o_wsc);

  k_actquant<<<TT, 256, 0, stream>>>(x, xq, asx);

  k_absum<<<256, 256, 0, stream>>>(wq, 2048 * 2048, prt + 0 * 256);
  k_absum<<<256, 256, 0, stream>>>(wk, 1024 * 2048, prt + 1 * 256);
  k_absum<<<256, 256, 0, stream>>>(wv, 1024 * 2048, prt + 2 * 256);
  k_absum<<<256, 256, 0, stream>>>(wo, 2048 * 2048, prt + 3 * 256);
  k_wscale<<<1, 256, 0, stream>>>(prt, wsc);

  k_wquant<<<512, 256, 0, stream>>>(wq, wqk, wsc + 0, 2048 * 2048);
  k_wquant<<<512, 256, 0, stream>>>(wk, wqk + 2048 * 2048, wsc + 1, 1024 * 2048);
  k_wquant<<<512, 256, 0, stream>>>(wv, wvt, wsc + 2, 1024 * 2048);
  k_wquant<<<512, 256, 0, stream>>>(wo, wot, wsc + 3, 2048 * 2048);

  k_gemm128<<<dim3(24, 16), 256, 0, stream>>>(xq, wqk, 0, qb, kb, nullptr, nullptr, asx, wsc);
  k_gemm128<<<dim3(16, 8), 256, 0, stream>>>(wvt, xq, 1, nullptr, nullptr, vth, vtl, asx, wsc + 2);

  k_normrope<<<dim3(TT, NHQ), 128, 0, stream>>>(qb, qn, cs, sn, qh, ql, NHQ, 0.08838834764831845f);
  k_normrope<<<dim3(TT, NKVH), 128, 0, stream>>>(kb, kn, cs, sn, kh, kl, NKVH, 1.0f);

  k_attn_mfma<<<dim3(16, 32), 256, 0, stream>>>(qh, ql, kh, kl, vth, vtl, ao);

  k_actquant<<<TT, 256, 0, stream>>>(ao, aq, as2);
  k_gemm128<<<dim3(16, 16), 256, 0, stream>>>(aq, wot, 2, out, nullptr, nullptr, nullptr, as2, wsc + 3);
}

// Round 5
// 176.897 us; speedup vs baseline: 6.5961x; 1.9073x over previous
//
#include <hip/hip_runtime.h>
#include <hip/hip_bf16.h>

#define TT   2048   // B*S tokens
#define HH   2048   // hidden dim
#define SEQ  1024
#define NHQ  16
#define NKVH 8
#define HDD  128

typedef __attribute__((ext_vector_type(8))) short short8;
typedef __attribute__((ext_vector_type(4))) float f32x4;
typedef __attribute__((ext_vector_type(4))) int int4v;

static __device__ __forceinline__ unsigned short f2bf(float f) {
  return (unsigned short)(__float_as_uint(f) >> 16);   // truncate; lo-term compensates
}
static __device__ __forceinline__ float bf2f(unsigned short u) {
  return __uint_as_float(((unsigned int)u) << 16);
}

#define GLD_LDS16(gp, lp)                                                        \
  __builtin_amdgcn_global_load_lds(                                              \
      (const __attribute__((address_space(1))) void*)(const void*)(gp),          \
      (__attribute__((address_space(3))) void*)(void*)(lp), 16, 0, 0)

// ---------------------------------------------------------------------------
// K1: per-row act_quant -> int8 (vectorized float4 loads, shfl reduce)
// ---------------------------------------------------------------------------
__global__ __launch_bounds__(256) void k_actquant(const float* __restrict__ x,
                                                  signed char* __restrict__ xq,
                                                  float* __restrict__ as_inv) {
  int row = blockIdx.x, tid = threadIdx.x;
  int wave = tid >> 6, lane = tid & 63;
  const float4* xr4 = (const float4*)(x + (size_t)row * HH);
  float4 a = xr4[tid * 2], b = xr4[tid * 2 + 1];
  float am = fmaxf(fmaxf(fmaxf(fabsf(a.x), fabsf(a.y)), fmaxf(fabsf(a.z), fabsf(a.w))),
                   fmaxf(fmaxf(fabsf(b.x), fabsf(b.y)), fmaxf(fabsf(b.z), fabsf(b.w))));
#pragma unroll
  for (int o = 32; o; o >>= 1) am = fmaxf(am, __shfl_xor(am, o));
  __shared__ float wred[4];
  if (lane == 0) wred[wave] = am;
  __syncthreads();
  am = fmaxf(fmaxf(wred[0], wred[1]), fmaxf(wred[2], wred[3]));
  am = fmaxf(am, 1e-5f);
  if (tid == 0) as_inv[row] = am / 127.f;
  float scale = 127.f / am;
  float vals[8] = {a.x, a.y, a.z, a.w, b.x, b.y, b.z, b.w};
  unsigned int u0 = 0, u1 = 0;
#pragma unroll
  for (int j = 0; j < 4; ++j) {
    int q = (int)fminf(fmaxf(rintf(vals[j] * scale), -128.f), 127.f);
    u0 |= (unsigned int)(q & 255) << (8 * j);
  }
#pragma unroll
  for (int j = 0; j < 4; ++j) {
    int q = (int)fminf(fmaxf(rintf(vals[4 + j] * scale), -128.f), 127.f);
    u1 |= (unsigned int)(q & 255) << (8 * j);
  }
  uint2 uu; uu.x = u0; uu.y = u1;
  ((uint2*)(xq + (size_t)row * HH))[tid] = uu;
}

// ---------------------------------------------------------------------------
// K2: deterministic partial |w| sums (f64), all 4 weights in one dispatch
// ---------------------------------------------------------------------------
__global__ __launch_bounds__(256) void k_absum_all(const float* __restrict__ wq,
                                                   const float* __restrict__ wk,
                                                   const float* __restrict__ wv,
                                                   const float* __restrict__ wo,
                                                   double* __restrict__ part) {
  int wid = blockIdx.y;
  const float* w = (wid == 0) ? wq : (wid == 1) ? wk : (wid == 2) ? wv : wo;
  int nq = ((wid == 0 || wid == 3) ? 4194304 : 2097152) >> 2;
  double s = 0.0;
  for (int i = blockIdx.x * 256 + threadIdx.x; i < nq; i += 256 * 256) {
    float4 v = ((const float4*)w)[i];
    s += (double)fabsf(v.x) + (double)fabsf(v.y) + (double)fabsf(v.z) + (double)fabsf(v.w);
  }
  __shared__ double red[256];
  red[threadIdx.x] = s;
  __syncthreads();
  for (int st = 128; st > 0; st >>= 1) {
    if (threadIdx.x < st) red[threadIdx.x] += red[threadIdx.x + st];
    __syncthreads();
  }
  if (threadIdx.x == 0) part[wid * 256 + blockIdx.x] = red[0];
}

__global__ __launch_bounds__(256) void k_wscale(const double* __restrict__ part,
                                                float* __restrict__ wsc) {
  __shared__ double red[256];
  const double nvals[4] = {4194304.0, 2097152.0, 2097152.0, 4194304.0};
  for (int w = 0; w < 4; ++w) {
    red[threadIdx.x] = part[w * 256 + threadIdx.x];
    __syncthreads();
    for (int st = 128; st > 0; st >>= 1) {
      if (threadIdx.x < st) red[threadIdx.x] += red[threadIdx.x + st];
      __syncthreads();
    }
    if (threadIdx.x == 0) {
      float mean = (float)(red[0] / nvals[w]);
      wsc[w] = fmaxf(mean, 1e-5f);
    }
    __syncthreads();
  }
}

// ---------------------------------------------------------------------------
// K3: ternary weight quant -> int8, all 4 weights in one dispatch (float4 in,
// char4-packed-uint out)
// ---------------------------------------------------------------------------
__global__ __launch_bounds__(256) void k_wquant_all(const float* __restrict__ wq,
                                                    const float* __restrict__ wk,
                                                    const float* __restrict__ wv,
                                                    const float* __restrict__ wo,
                                                    signed char* __restrict__ wqk,
                                                    signed char* __restrict__ wvt,
                                                    signed char* __restrict__ wot,
                                                    const float* __restrict__ wsc) {
  const int NQ = 3145728;   // total quads (12.58M elems / 4)
  for (int qi = blockIdx.x * 256 + threadIdx.x; qi < NQ; qi += gridDim.x * 256) {
    const float* src; signed char* dst; float inv; int off;
    if (qi < 1048576)      { src = wq; dst = wqk;           off = qi;           inv = 1.f / wsc[0]; }
    else if (qi < 1572864) { src = wk; dst = wqk + 4194304; off = qi - 1048576; inv = 1.f / wsc[1]; }
    else if (qi < 2097152) { src = wv; dst = wvt;           off = qi - 1572864; inv = 1.f / wsc[2]; }
    else                   { src = wo; dst = wot;           off = qi - 2097152; inv = 1.f / wsc[3]; }
    float4 v = ((const float4*)src)[off];
    unsigned int u = 0;
    float vv[4] = {v.x, v.y, v.z, v.w};
#pragma unroll
    for (int j = 0; j < 4; ++j) {
      int q = (int)fminf(fmaxf(rintf(vv[j] * inv), -1.f), 1.f);
      u |= (unsigned int)(q & 255) << (8 * j);
    }
    ((unsigned int*)dst)[off] = u;
  }
}

// ---------------------------------------------------------------------------
// K4: i8 MFMA NT-GEMM, 128x128 tile, BK=64, global_load_lds staging,
// source-side XOR swizzle (4-way conflict instead of 8-way).
// which==0: 512 blocks = 384 QK tiles (A=xq,B=wqk; f32 out q/k) +
//           128 V tiles (A=wvt feats, B=xq tokens; hi/lo bf16 transposed out)
// which==1: 256 blocks, O projection (A=aq, B=wot; f32 out, scale wsc[3])
// ---------------------------------------------------------------------------
__global__ __launch_bounds__(256) void k_gemm_i8(const signed char* __restrict__ A0,
                                                 const signed char* __restrict__ B0,
                                                 const signed char* __restrict__ B1,
                                                 int which,
                                                 float* __restrict__ d0,
                                                 float* __restrict__ d1,
                                                 unsigned short* __restrict__ dh,
                                                 unsigned short* __restrict__ dl,
                                                 const float* __restrict__ asx,
                                                 const float* __restrict__ wsc) {
  const int K = HH;
  __shared__ signed char As[8192];   // [128][64] (source-swizzled within 64B rows)
  __shared__ signed char Bs[8192];
  int tid = threadIdx.x;
  int wave = tid >> 6, lane = tid & 63, l15 = lane & 15, g = lane >> 4;
  int wm = wave >> 1, wn = wave & 1;

  const signed char *Ap, *Bp;
  int bm, bn, mode;
  if (which == 0) {
    int gid = (blockIdx.x & 7) * 64 + (blockIdx.x >> 3);   // XCD chunk, 512 blocks
    if (gid < 384) { mode = 0; bm = (gid / 24) * 128; bn = (gid % 24) * 128; Ap = A0; Bp = B0; }
    else { mode = 1; int vid = gid - 384; bm = (vid >> 4) * 128; bn = (vid & 15) * 128; Ap = B1; Bp = A0; }
  } else {
    int gid = (blockIdx.x & 7) * 32 + (blockIdx.x >> 3);   // 256 blocks
    mode = 2; bm = (gid >> 4) * 128; bn = (gid & 15) * 128; Ap = A0; Bp = B0;
  }

  int4v acc[4][4] = {};
  for (int k0 = 0; k0 < K; k0 += 64) {
    __syncthreads();
#pragma unroll
    for (int r = 0; r < 2; ++r) {
      int c = r * 256 + tid;
      int row = c >> 2;
      int kk = ((c & 3) << 4) ^ ((row & 3) << 4);     // pre-swizzled source
      GLD_LDS16(Ap + (size_t)(bm + row) * K + k0 + kk, As + c * 16);
      GLD_LDS16(Bp + (size_t)(bn + row) * K + k0 + kk, Bs + c * 16);
    }
    __syncthreads();
    int4v af[4], bf[4];
#pragma unroll
    for (int i = 0; i < 4; ++i) {
      int ra = wm * 64 + i * 16 + l15;
      af[i] = *(const int4v*)&As[ra * 64 + ((g * 16) ^ ((ra & 3) << 4))];
      int rb = wn * 64 + i * 16 + l15;
      bf[i] = *(const int4v*)&Bs[rb * 64 + ((g * 16) ^ ((rb & 3) << 4))];
    }
#pragma unroll
    for (int mi = 0; mi < 4; ++mi)
#pragma unroll
      for (int ni = 0; ni < 4; ++ni)
        acc[mi][ni] = __builtin_amdgcn_mfma_i32_16x16x64_i8(af[mi], bf[ni], acc[mi][ni], 0, 0, 0);
  }

#pragma unroll
  for (int mi = 0; mi < 4; ++mi) {
#pragma unroll
    for (int rr = 0; rr < 4; ++rr) {
      int crow = bm + wm * 64 + mi * 16 + 4 * g + rr;   // C/D: row=(lane>>4)*4+reg
      if (mode == 0) {
        float rs = asx[crow];
        float w0 = wsc[0], w1 = wsc[1];
#pragma unroll
        for (int ni = 0; ni < 4; ++ni) {
          int ccol = bn + wn * 64 + ni * 16 + l15;
          float v = (float)acc[mi][ni][rr] * rs;
          if (ccol < 2048) d0[(size_t)crow * 2048 + ccol] = v * w0;
          else             d1[(size_t)crow * 1024 + ccol - 2048] = v * w1;
        }
      } else if (mode == 2) {
        float rs = asx[crow] * wsc[3];
#pragma unroll
        for (int ni = 0; ni < 4; ++ni) {
          int ccol = bn + wn * 64 + ni * 16 + l15;
          d0[(size_t)crow * 2048 + ccol] = (float)acc[mi][ni][rr] * rs;
        }
      } else {   // mode 1: V hi/lo transposed (crow=feature, ccol=token)
        float w2 = wsc[2];
#pragma unroll
        for (int ni = 0; ni < 4; ++ni) {
          int ccol = bn + wn * 64 + ni * 16 + l15;
          float v = (float)acc[mi][ni][rr] * asx[ccol] * w2;
          unsigned short hi = f2bf(v);
          size_t ad = ((size_t)((ccol >> 10) * 1024 + crow)) * 1024 + (ccol & 1023);
          dh[ad] = hi;
          dl[ad] = f2bf(v - bf2f(hi));
        }
      }
    }
  }
}

// ---------------------------------------------------------------------------
// K5: fused q+k rmsnorm+rope, wave-per-row, shfl-only. -> bf16 hi/lo
// ---------------------------------------------------------------------------
__global__ __launch_bounds__(256) void k_normrope_all(const float* __restrict__ qb,
                                                      const float* __restrict__ kb,
                                                      const float* __restrict__ qn,
                                                      const float* __restrict__ kn,
                                                      const float* __restrict__ cs,
                                                      const float* __restrict__ sn,
                                                      unsigned short* __restrict__ qh,
                                                      unsigned short* __restrict__ ql,
                                                      unsigned short* __restrict__ kh,
                                                      unsigned short* __restrict__ kl) {
  int wave = threadIdx.x >> 6, lane = threadIdx.x & 63;
  int rid = blockIdx.x * 4 + wave;        // 0..49151
  const float *src, *nwp;
  unsigned short *oh, *ol;
  float ps;
  int tok;
  if (rid < 32768) {
    src = qb + (size_t)rid * 128; nwp = qn;
    oh = qh + (size_t)rid * 128; ol = ql + (size_t)rid * 128;
    ps = 0.08838834764831845f; tok = rid >> 4;
  } else {
    int r2 = rid - 32768;
    src = kb + (size_t)r2 * 128; nwp = kn;
    oh = kh + (size_t)r2 * 128; ol = kl + (size_t)r2 * 128;
    ps = 1.f; tok = r2 >> 3;
  }
  int s = tok & (SEQ - 1);
  float2 v = ((const float2*)src)[lane];
  float ss = v.x * v.x + v.y * v.y;
#pragma unroll
  for (int o = 32; o; o >>= 1) ss += __shfl_xor(ss, o);
  float inv = rsqrtf(ss * (1.f / 128.f) + 1e-6f);
  float2 nwv = ((const float2*)nwp)[lane];
  float nx = nwv.x * (v.x * inv), ny = nwv.y * (v.y * inv);
  float ox = __shfl_xor(nx, 32), oy = __shfl_xor(ny, 32);
  float rx = (lane < 32) ? -ox : ox;
  float ry = (lane < 32) ? -oy : oy;
  float2 c2 = ((const float2*)(cs + (size_t)s * 128))[lane];
  float2 s2 = ((const float2*)(sn + (size_t)s * 128))[lane];
  float resx = (nx * c2.x + rx * s2.x) * ps;
  float resy = (ny * c2.y + ry * s2.y) * ps;
  unsigned short hx = f2bf(resx), hy = f2bf(resy);
  ((unsigned int*)oh)[lane] = (unsigned int)hx | ((unsigned int)hy << 16);
  unsigned short lx = f2bf(resx - bf2f(hx)), ly = f2bf(resy - bf2f(hy));
  ((unsigned int*)ol)[lane] = (unsigned int)lx | ((unsigned int)ly << 16);
}

// ---------------------------------------------------------------------------
// K6: MFMA flash attention (unchanged from round 4)
// ---------------------------------------------------------------------------
__global__ __launch_bounds__(256) void k_attn_mfma(const unsigned short* __restrict__ qhp,
                                                   const unsigned short* __restrict__ qlp,
                                                   const unsigned short* __restrict__ khp,
                                                   const unsigned short* __restrict__ klp,
                                                   const unsigned short* __restrict__ vhp,
                                                   const unsigned short* __restrict__ vlp,
                                                   float* __restrict__ o) {
  int i = blockIdx.x + blockIdx.y * 16;
  int w = (i & 7) * 64 + (i >> 3);
  int y = w >> 4;
  int widx = w & 15;
  int qt = (widx & 1) ? (widx >> 1) : (15 - (widx >> 1));
  int b = y >> 4, h = y & 15, kvh = h >> 1;
  int wave = threadIdx.x >> 6, lane = threadIdx.x & 63;
  int l15 = lane & 15, g = lane >> 4;
  int q0b = qt * 64;
  int q0w = q0b + wave * 16;
  int qglob = q0w + l15;

  __shared__ unsigned short Kh[2][4096], Kl[2][4096];
  __shared__ unsigned short Vh[2][4096], Vl[2][4096];
  __shared__ unsigned short Plds[4][2][16][40];

  short8 qfh[4], qfl[4];
  {
    const unsigned short* qb = qhp + ((size_t)(b * SEQ + qglob) * NHQ + h) * HDD + g * 8;
    const unsigned short* ql = qlp + ((size_t)(b * SEQ + qglob) * NHQ + h) * HDD + g * 8;
#pragma unroll
    for (int c = 0; c < 4; ++c) {
      qfh[c] = *(const short8*)(qb + c * 32);
      qfl[c] = *(const short8*)(ql + c * 32);
    }
  }

#define STAGE(KV0N, BFN)                                                              \
  {                                                                                   \
    int c0 = wave * 64 + lane;                                                        \
    _Pragma("unroll")                                                                 \
    for (int tch = 0; tch < 2; ++tch) {                                               \
      int c = tch * 256 + c0;                                                         \
      int ki = c >> 4, j = (c & 15) << 4;                                             \
      int js = j ^ ((ki & 7) << 4);                                                   \
      size_t kbase = ((size_t)(b * SEQ + (KV0N) + ki) * NKVH + kvh) * HDD;            \
      GLD_LDS16((const char*)(khp + kbase) + js, &Kh[BFN][c * 8]);                    \
      GLD_LDS16((const char*)(klp + kbase) + js, &Kl[BFN][c * 8]);                    \
      int d = c >> 2, jv = (c & 3) << 4;                                              \
      int jvs = jv ^ ((d & 3) << 4);                                                  \
      size_t vbase = ((size_t)(b * 1024 + kvh * 128 + d)) * SEQ + (KV0N);             \
      GLD_LDS16((const char*)(vhp + vbase) + jvs, &Vh[BFN][c * 8]);                   \
      GLD_LDS16((const char*)(vlp + vbase) + jvs, &Vl[BFN][c * 8]);                   \
    }                                                                                 \
  }

  f32x4 acc[8] = {};
  float m_run = -INFINITY, l_run = 0.f;
  int nkv = 2 * qt + 2;

  STAGE(0, 0);
  __syncthreads();

  int bf = 0;
  for (int kv = 0; kv < nkv; ++kv) {
    int kv0 = kv * 32;
    if (kv + 1 < nkv) STAGE(kv0 + 32, bf ^ 1);
    bool active = (kv0 <= q0w + 15);
    if (active) {
      float sc[2][4];
#pragma unroll
      for (int t = 0; t < 2; ++t) {
        int row = 16 * t + l15;
        int rbyte = row * 256, sw = (row & 7) << 4;
        f32x4 s = {0.f, 0.f, 0.f, 0.f};
#pragma unroll
        for (int c = 0; c < 4; ++c) {
          int off = rbyte + ((c * 64 + g * 16) ^ sw);
          short8 kfh = *(const short8*)((const char*)&Kh[bf][0] + off);
          short8 kfl = *(const short8*)((const char*)&Kl[bf][0] + off);
          s = __builtin_amdgcn_mfma_f32_16x16x32_bf16(kfh, qfh[c], s, 0, 0, 0);
          s = __builtin_amdgcn_mfma_f32_16x16x32_bf16(kfl, qfh[c], s, 0, 0, 0);
          s = __builtin_amdgcn_mfma_f32_16x16x32_bf16(kfh, qfl[c], s, 0, 0, 0);
        }
#pragma unroll
        for (int r = 0; r < 4; ++r) sc[t][r] = s[r];
      }
      if (kv0 + 31 > q0w) {
#pragma unroll
        for (int t = 0; t < 2; ++t)
#pragma unroll
          for (int r = 0; r < 4; ++r)
            if (kv0 + 16 * t + 4 * g + r > qglob) sc[t][r] = -INFINITY;
      }
      float mx = m_run;
#pragma unroll
      for (int t = 0; t < 2; ++t)
#pragma unroll
        for (int r = 0; r < 4; ++r) mx = fmaxf(mx, sc[t][r]);
      mx = fmaxf(mx, __shfl_xor(mx, 16));
      mx = fmaxf(mx, __shfl_xor(mx, 32));
      float corr = __expf(m_run - mx);
      m_run = mx;
      float psum = 0.f;
      unsigned short ph[2][4], plo[2][4];
#pragma unroll
      for (int t = 0; t < 2; ++t)
#pragma unroll
        for (int r = 0; r < 4; ++r) {
          float p = __expf(sc[t][r] - mx);
          psum += p;
          unsigned short hi = f2bf(p);
          ph[t][r] = hi;
          plo[t][r] = f2bf(p - bf2f(hi));
        }
      psum += __shfl_xor(psum, 16);
      psum += __shfl_xor(psum, 32);
      l_run = l_run * corr + psum;
      float corro[4];
#pragma unroll
      for (int r = 0; r < 4; ++r) corro[r] = __shfl(corr, 4 * g + r);
#pragma unroll
      for (int dt = 0; dt < 8; ++dt)
#pragma unroll
        for (int r = 0; r < 4; ++r) acc[dt][r] *= corro[r];
      ushort4 wh, wl;
#pragma unroll
      for (int t = 0; t < 2; ++t) {
        wh.x = ph[t][0]; wh.y = ph[t][1]; wh.z = ph[t][2]; wh.w = ph[t][3];
        wl.x = plo[t][0]; wl.y = plo[t][1]; wl.z = plo[t][2]; wl.w = plo[t][3];
        *(ushort4*)&Plds[wave][0][l15][16 * t + 4 * g] = wh;
        *(ushort4*)&Plds[wave][1][l15][16 * t + 4 * g] = wl;
      }
      short8 pah = *(const short8*)&Plds[wave][0][l15][8 * g];
      short8 pal = *(const short8*)&Plds[wave][1][l15][8 * g];
#pragma unroll
      for (int dt = 0; dt < 8; ++dt) {
        int d = dt * 16 + l15;
        int off = d * 64 + ((g * 16) ^ ((d & 3) << 4));
        short8 vfh = *(const short8*)((const char*)&Vh[bf][0] + off);
        short8 vfl = *(const short8*)((const char*)&Vl[bf][0] + off);
        acc[dt] = __builtin_amdgcn_mfma_f32_16x16x32_bf16(pah, vfh, acc[dt], 0, 0, 0);
        acc[dt] = __builtin_amdgcn_mfma_f32_16x16x32_bf16(pal, vfh, acc[dt], 0, 0, 0);
        acc[dt] = __builtin_amdgcn_mfma_f32_16x16x32_bf16(pah, vfl, acc[dt], 0, 0, 0);
      }
    }
    __syncthreads();
    bf ^= 1;
  }
#undef STAGE

  float linv = 1.f / l_run;
  float lrow[4];
#pragma unroll
  for (int r = 0; r < 4; ++r) lrow[r] = __shfl(linv, 4 * g + r);
#pragma unroll
  for (int r = 0; r < 4; ++r) {
    size_t orow = ((size_t)(b * SEQ + q0w + 4 * g + r) * NHQ + h) * HDD + l15;
#pragma unroll
    for (int dt = 0; dt < 8; ++dt)
      o[orow + dt * 16] = acc[dt][r] * lrow[r];
  }
}

// ---------------------------------------------------------------------------
extern "C" void kernel_launch(void* const* d_in, const int* in_sizes, int n_in,
                              void* d_out, int out_size, void* d_ws, size_t ws_size,
                              hipStream_t stream) {
  const float* x  = (const float*)d_in[0];
  const float* cs = (const float*)d_in[1];
  const float* sn = (const float*)d_in[2];
  const float* wq = (const float*)d_in[3];
  const float* wk = (const float*)d_in[4];
  const float* wv = (const float*)d_in[5];
  const float* wo = (const float*)d_in[6];
  const float* qn = (const float*)d_in[7];
  const float* kn = (const float*)d_in[8];
  float* out = (float*)d_out;
  char* ws = (char*)d_ws;

  const size_t MB = 1024 * 1024;
  size_t o_xq  = 0;            // 4 MB  int8 xq
  size_t o_wqk = 4  * MB;      // 6 MB  [3072][2048] i8
  size_t o_wvt = 10 * MB;      // 2 MB  [1024][2048] i8
  size_t o_wot = 12 * MB;      // 4 MB  [2048][2048] i8
  size_t o_qb  = 16 * MB;      // 16 MB f32 q proj -> later ao
  size_t o_kb  = 32 * MB;      // 8 MB  f32 k proj -> later aq (4 MB)
  size_t o_vth = 40 * MB;      // 4 MB
  size_t o_vtl = 44 * MB;      // 4 MB
  size_t o_qh  = 48 * MB;      // 8 MB
  size_t o_ql  = 56 * MB;      // 8 MB
  size_t o_kh  = 64 * MB;      // 4 MB
  size_t o_kl  = 68 * MB;      // 4 MB
  size_t o_as  = 72 * MB;
  size_t o_as2 = o_as  + 8192;
  size_t o_prt = o_as2 + 8192;
  size_t o_wsc = o_prt + 8192;

  signed char* xq  = (signed char*)(ws + o_xq);
  signed char* wqk = (signed char*)(ws + o_wqk);
  signed char* wvt = (signed char*)(ws + o_wvt);
  signed char* wot = (signed char*)(ws + o_wot);
  float* qb  = (float*)(ws + o_qb);
  float* kb  = (float*)(ws + o_kb);
  unsigned short* vth = (unsigned short*)(ws + o_vth);
  unsigned short* vtl = (unsigned short*)(ws + o_vtl);
  unsigned short* qh  = (unsigned short*)(ws + o_qh);
  unsigned short* ql  = (unsigned short*)(ws + o_ql);
  unsigned short* kh  = (unsigned short*)(ws + o_kh);
  unsigned short* kl  = (unsigned short*)(ws + o_kl);
  float* ao = qb;                               // reuse
  signed char* aq = (signed char*)kb;           // reuse
  float* asx = (float*)(ws + o_as);
  float* as2 = (float*)(ws + o_as2);
  double* prt = (double*)(ws + o_prt);
  float* wsc = (float*)(ws + o_wsc);

  // 1) activation quant of x -> int8
  k_actquant<<<TT, 256, 0, stream>>>(x, xq, asx);

  // 2) weight scales (one dispatch) + finalize
  k_absum_all<<<dim3(256, 4), 256, 0, stream>>>(wq, wk, wv, wo, prt);
  k_wscale<<<1, 256, 0, stream>>>(prt, wsc);

  // 3) ternary weight quant -> int8 (one dispatch)
  k_wquant_all<<<2048, 256, 0, stream>>>(wq, wk, wv, wo, wqk, wvt, wot, wsc);

  // 4) fused QKV projection (i8 MFMA), one 512-block dispatch
  k_gemm_i8<<<512, 256, 0, stream>>>(xq, wqk, wvt, 0, qb, kb, vth, vtl, asx, wsc);

  // 5) fused rmsnorm+rope (q and k in one dispatch)
  k_normrope_all<<<12288, 256, 0, stream>>>(qb, kb, qn, kn, cs, sn, qh, ql, kh, kl);

  // 6) MFMA flash attention
  k_attn_mfma<<<dim3(16, 32), 256, 0, stream>>>(qh, ql, kh, kl, vth, vtl, ao);

  // 7) re-quant + output projection (i8 MFMA)
  k_actquant<<<TT, 256, 0, stream>>>(ao, aq, as2);
  k_gemm_i8<<<256, 256, 0, stream>>>(aq, wot, nullptr, 1, out, nullptr, nullptr, nullptr, as2, wsc);
}

// Round 6
// 159.660 us; speedup vs baseline: 7.3082x; 1.1080x over previous
//
#include <hip/hip_runtime.h>
#include <hip/hip_bf16.h>

#define TT   2048   // B*S tokens
#define HH   2048   // hidden dim
#define SEQ  1024
#define NHQ  16
#define NKVH 8
#define HDD  128

typedef __attribute__((ext_vector_type(8))) short short8;
typedef __attribute__((ext_vector_type(4))) float f32x4;
typedef __attribute__((ext_vector_type(4))) int int4v;
typedef _Float16 half8 __attribute__((ext_vector_type(8)));

static __device__ __forceinline__ unsigned short f2bf(float f) {
  return (unsigned short)(__float_as_uint(f) >> 16);   // truncate; lo-term compensates
}
static __device__ __forceinline__ float bf2f(unsigned short u) {
  return __uint_as_float(((unsigned int)u) << 16);
}
static __device__ __forceinline__ unsigned short f2h(float f) {
  union { _Float16 h; unsigned short u; } c;
  c.h = (_Float16)f;
  return c.u;
}
static __device__ __forceinline__ half8 s2h(short8 v) {
  union { short8 s; half8 h; } c;
  c.s = v;
  return c.h;
}

#define GLD_LDS16(gp, lp)                                                        \
  __builtin_amdgcn_global_load_lds(                                              \
      (const __attribute__((address_space(1))) void*)(const void*)(gp),          \
      (__attribute__((address_space(3))) void*)(void*)(lp), 16, 0, 0)

// ---------------------------------------------------------------------------
// K1: per-row act_quant -> int8 (vectorized float4 loads, shfl reduce)
// ---------------------------------------------------------------------------
__global__ __launch_bounds__(256) void k_actquant(const float* __restrict__ x,
                                                  signed char* __restrict__ xq,
                                                  float* __restrict__ as_inv) {
  int row = blockIdx.x, tid = threadIdx.x;
  int wave = tid >> 6, lane = tid & 63;
  const float4* xr4 = (const float4*)(x + (size_t)row * HH);
  float4 a = xr4[tid * 2], b = xr4[tid * 2 + 1];
  float am = fmaxf(fmaxf(fmaxf(fabsf(a.x), fabsf(a.y)), fmaxf(fabsf(a.z), fabsf(a.w))),
                   fmaxf(fmaxf(fabsf(b.x), fabsf(b.y)), fmaxf(fabsf(b.z), fabsf(b.w))));
#pragma unroll
  for (int o = 32; o; o >>= 1) am = fmaxf(am, __shfl_xor(am, o));
  __shared__ float wred[4];
  if (lane == 0) wred[wave] = am;
  __syncthreads();
  am = fmaxf(fmaxf(wred[0], wred[1]), fmaxf(wred[2], wred[3]));
  am = fmaxf(am, 1e-5f);
  if (tid == 0) as_inv[row] = am / 127.f;
  float scale = 127.f / am;
  float vals[8] = {a.x, a.y, a.z, a.w, b.x, b.y, b.z, b.w};
  unsigned int u0 = 0, u1 = 0;
#pragma unroll
  for (int j = 0; j < 4; ++j) {
    int q = (int)fminf(fmaxf(rintf(vals[j] * scale), -128.f), 127.f);
    u0 |= (unsigned int)(q & 255) << (8 * j);
  }
#pragma unroll
  for (int j = 0; j < 4; ++j) {
    int q = (int)fminf(fmaxf(rintf(vals[4 + j] * scale), -128.f), 127.f);
    u1 |= (unsigned int)(q & 255) << (8 * j);
  }
  uint2 uu; uu.x = u0; uu.y = u1;
  ((uint2*)(xq + (size_t)row * HH))[tid] = uu;
}

// ---------------------------------------------------------------------------
// K2: deterministic partial |w| sums (f64), all 4 weights in one dispatch
// ---------------------------------------------------------------------------
__global__ __launch_bounds__(256) void k_absum_all(const float* __restrict__ wq,
                                                   const float* __restrict__ wk,
                                                   const float* __restrict__ wv,
                                                   const float* __restrict__ wo,
                                                   double* __restrict__ part) {
  int wid = blockIdx.y;
  const float* w = (wid == 0) ? wq : (wid == 1) ? wk : (wid == 2) ? wv : wo;
  int nq = ((wid == 0 || wid == 3) ? 4194304 : 2097152) >> 2;
  double s = 0.0;
  for (int i = blockIdx.x * 256 + threadIdx.x; i < nq; i += 256 * 256) {
    float4 v = ((const float4*)w)[i];
    s += (double)fabsf(v.x) + (double)fabsf(v.y) + (double)fabsf(v.z) + (double)fabsf(v.w);
  }
  __shared__ double red[256];
  red[threadIdx.x] = s;
  __syncthreads();
  for (int st = 128; st > 0; st >>= 1) {
    if (threadIdx.x < st) red[threadIdx.x] += red[threadIdx.x + st];
    __syncthreads();
  }
  if (threadIdx.x == 0) part[wid * 256 + blockIdx.x] = red[0];
}

__global__ __launch_bounds__(256) void k_wscale(const double* __restrict__ part,
                                                float* __restrict__ wsc) {
  __shared__ double red[256];
  const double nvals[4] = {4194304.0, 2097152.0, 2097152.0, 4194304.0};
  for (int w = 0; w < 4; ++w) {
    red[threadIdx.x] = part[w * 256 + threadIdx.x];
    __syncthreads();
    for (int st = 128; st > 0; st >>= 1) {
      if (threadIdx.x < st) red[threadIdx.x] += red[threadIdx.x + st];
      __syncthreads();
    }
    if (threadIdx.x == 0) {
      float mean = (float)(red[0] / nvals[w]);
      wsc[w] = fmaxf(mean, 1e-5f);
    }
    __syncthreads();
  }
}

// ---------------------------------------------------------------------------
// K3: ternary weight quant -> int8, all 4 weights in one dispatch
// ---------------------------------------------------------------------------
__global__ __launch_bounds__(256) void k_wquant_all(const float* __restrict__ wq,
                                                    const float* __restrict__ wk,
                                                    const float* __restrict__ wv,
                                                    const float* __restrict__ wo,
                                                    signed char* __restrict__ wqk,
                                                    signed char* __restrict__ wvt,
                                                    signed char* __restrict__ wot,
                                                    const float* __restrict__ wsc) {
  const int NQ = 3145728;
  for (int qi = blockIdx.x * 256 + threadIdx.x; qi < NQ; qi += gridDim.x * 256) {
    const float* src; signed char* dst; float inv; int off;
    if (qi < 1048576)      { src = wq; dst = wqk;           off = qi;           inv = 1.f / wsc[0]; }
    else if (qi < 1572864) { src = wk; dst = wqk + 4194304; off = qi - 1048576; inv = 1.f / wsc[1]; }
    else if (qi < 2097152) { src = wv; dst = wvt;           off = qi - 1572864; inv = 1.f / wsc[2]; }
    else                   { src = wo; dst = wot;           off = qi - 2097152; inv = 1.f / wsc[3]; }
    float4 v = ((const float4*)src)[off];
    unsigned int u = 0;
    float vv[4] = {v.x, v.y, v.z, v.w};
#pragma unroll
    for (int j = 0; j < 4; ++j) {
      int q = (int)fminf(fmaxf(rintf(vv[j] * inv), -1.f), 1.f);
      u |= (unsigned int)(q & 255) << (8 * j);
    }
    ((unsigned int*)dst)[off] = u;
  }
}

// ---------------------------------------------------------------------------
// K4: i8 MFMA NT-GEMM, 128x128 tile, BK=64, global_load_lds staging,
// source-side XOR swizzle.
// which==0: 512 blocks = 384 QK tiles (fused rmsnorm+rope epilogue -> bf16
//           hi/lo qh/ql/kh/kl directly) + 128 V tiles (fp16 transposed vt)
// which==1: 256 blocks, O projection (f32 out, scale wsc[3])
// mode-0 col remap: wave cols = wn*32+(ni&1)*16+(ni>>1)*64+l15 so each lane
// holds both rope partners (d, d^64) in registers (partner = ni^2).
// ---------------------------------------------------------------------------
__global__ __launch_bounds__(256) void k_gemm_i8(const signed char* __restrict__ A0,
                                                 const signed char* __restrict__ B0,
                                                 const signed char* __restrict__ B1,
                                                 int which,
                                                 float* __restrict__ d0,
                                                 unsigned short* __restrict__ dh,
                                                 const float* __restrict__ asx,
                                                 const float* __restrict__ wsc,
                                                 const float* __restrict__ qn,
                                                 const float* __restrict__ kn,
                                                 const float* __restrict__ cs,
                                                 const float* __restrict__ sn,
                                                 unsigned short* __restrict__ qh,
                                                 unsigned short* __restrict__ ql,
                                                 unsigned short* __restrict__ kh,
                                                 unsigned short* __restrict__ kl) {
  const int K = HH;
  __shared__ signed char As[8192];   // [128][64] (source-swizzled within rows)
  __shared__ signed char Bs[8192];
  int tid = threadIdx.x;
  int wave = tid >> 6, lane = tid & 63, l15 = lane & 15, g = lane >> 4;
  int wm = wave >> 1, wn = wave & 1;

  const signed char *Ap, *Bp;
  int bm, bn, mode;
  if (which == 0) {
    int gid = (blockIdx.x & 7) * 64 + (blockIdx.x >> 3);   // XCD chunk, 512 blocks
    if (gid < 384) { mode = 0; bm = (gid / 24) * 128; bn = (gid % 24) * 128; Ap = A0; Bp = B0; }
    else { mode = 1; int vid = gid - 384; bm = (vid >> 4) * 128; bn = (vid & 15) * 128; Ap = B1; Bp = A0; }
  } else {
    int gid = (blockIdx.x & 7) * 32 + (blockIdx.x >> 3);   // 256 blocks
    mode = 2; bm = (gid >> 4) * 128; bn = (gid & 15) * 128; Ap = A0; Bp = B0;
  }

  int4v acc[4][4] = {};
  for (int k0 = 0; k0 < K; k0 += 64) {
    __syncthreads();
#pragma unroll
    for (int r = 0; r < 2; ++r) {
      int c = r * 256 + tid;
      int row = c >> 2;
      int kk = ((c & 3) << 4) ^ ((row & 3) << 4);
      GLD_LDS16(Ap + (size_t)(bm + row) * K + k0 + kk, As + c * 16);
      GLD_LDS16(Bp + (size_t)(bn + row) * K + k0 + kk, Bs + c * 16);
    }
    __syncthreads();
    int4v af[4], bf[4];
#pragma unroll
    for (int i = 0; i < 4; ++i) {
      int ra = wm * 64 + i * 16 + l15;
      af[i] = *(const int4v*)&As[ra * 64 + ((g * 16) ^ ((ra & 3) << 4))];
      int rb = (mode == 0) ? (wn * 32 + (i & 1) * 16 + (i >> 1) * 64 + l15)
                           : (wn * 64 + i * 16 + l15);
      bf[i] = *(const int4v*)&Bs[rb * 64 + ((g * 16) ^ ((rb & 3) << 4))];
    }
#pragma unroll
    for (int mi = 0; mi < 4; ++mi)
#pragma unroll
      for (int ni = 0; ni < 4; ++ni)
        acc[mi][ni] = __builtin_amdgcn_mfma_i32_16x16x64_i8(af[mi], bf[ni], acc[mi][ni], 0, 0, 0);
  }

  if (mode == 0) {
    // fused rmsnorm + rope epilogue
    bool isq = (bn < 2048);
    int hh = isq ? (bn >> 7) : ((bn - 2048) >> 7);
    float wN = isq ? wsc[0] : wsc[1];
    float ps = isq ? 0.08838834764831845f : 1.0f;
    const float* nw = isq ? qn : kn;
    unsigned short* oh = isq ? qh : kh;
    unsigned short* ol = isq ? ql : kl;
    int nhp = isq ? NHQ : NKVH;
    float* S = (float*)As;               // reuse LDS: [2][128] f32
    __syncthreads();                     // all waves done reading As/Bs
#pragma unroll
    for (int mi = 0; mi < 4; ++mi) {
#pragma unroll
      for (int rr = 0; rr < 4; ++rr) {
        int tok = bm + wm * 64 + mi * 16 + 4 * g + rr;
        float rs = asx[tok] * wN;
        float ssum = 0.f;
#pragma unroll
        for (int ni = 0; ni < 4; ++ni) {
          float v = (float)acc[mi][ni][rr] * rs;
          ssum += v * v;
        }
        ssum += __shfl_xor(ssum, 1); ssum += __shfl_xor(ssum, 2);
        ssum += __shfl_xor(ssum, 4); ssum += __shfl_xor(ssum, 8);
        if (l15 == 0) S[wn * 128 + wm * 64 + mi * 16 + 4 * g + rr] = ssum;
      }
    }
    __syncthreads();
#pragma unroll
    for (int mi = 0; mi < 4; ++mi) {
#pragma unroll
      for (int rr = 0; rr < 4; ++rr) {
        int rloc = wm * 64 + mi * 16 + 4 * g + rr;
        int tok = bm + rloc;
        float rs = asx[tok] * wN;
        float inv = rsqrtf((S[rloc] + S[128 + rloc]) * (1.f / 128.f) + 1e-6f);
        int s = tok & (SEQ - 1);
        float nv[4];
#pragma unroll
        for (int ni = 0; ni < 4; ++ni) {
          int d = wn * 32 + (ni & 1) * 16 + (ni >> 1) * 64 + l15;
          nv[ni] = nw[d] * ((float)acc[mi][ni][rr] * rs) * inv;
        }
#pragma unroll
        for (int ni = 0; ni < 4; ++ni) {
          int d = wn * 32 + (ni & 1) * 16 + (ni >> 1) * 64 + l15;
          float oo = nv[ni ^ 2];
          float rh = (ni < 2) ? -oo : oo;
          float res = (nv[ni] * cs[s * 128 + d] + rh * sn[s * 128 + d]) * ps;
          unsigned short hb = f2bf(res);
          size_t oi = ((size_t)tok * nhp + hh) * 128 + d;
          oh[oi] = hb;
          ol[oi] = f2bf(res - bf2f(hb));
        }
      }
    }
  } else if (mode == 2) {
#pragma unroll
    for (int mi = 0; mi < 4; ++mi) {
#pragma unroll
      for (int rr = 0; rr < 4; ++rr) {
        int crow = bm + wm * 64 + mi * 16 + 4 * g + rr;
        float rs = asx[crow] * wsc[3];
#pragma unroll
        for (int ni = 0; ni < 4; ++ni) {
          int ccol = bn + wn * 64 + ni * 16 + l15;
          d0[(size_t)crow * 2048 + ccol] = (float)acc[mi][ni][rr] * rs;
        }
      }
    }
  } else {   // mode 1: V fp16 transposed (crow=feature, ccol=token)
    float w2 = wsc[2];
#pragma unroll
    for (int mi = 0; mi < 4; ++mi) {
#pragma unroll
      for (int rr = 0; rr < 4; ++rr) {
        int crow = bm + wm * 64 + mi * 16 + 4 * g + rr;
#pragma unroll
        for (int ni = 0; ni < 4; ++ni) {
          int ccol = bn + wn * 64 + ni * 16 + l15;
          float v = (float)acc[mi][ni][rr] * asx[ccol] * w2;
          size_t ad = ((size_t)((ccol >> 10) * 1024 + crow)) * 1024 + (ccol & 1023);
          dh[ad] = f2h(v);
        }
      }
    }
  }
}

// ---------------------------------------------------------------------------
// K6: MFMA flash attention. QK^T: bf16 hi/lo (exact); P,V: single fp16.
// 4 waves/block, Q-tile 64, KV tile 32, LDS double-buffered via
// global_load_lds with source-side XOR swizzle. 54272 B LDS -> 3 blocks/CU.
// ---------------------------------------------------------------------------
__global__ __launch_bounds__(256) void k_attn_mfma(const unsigned short* __restrict__ qhp,
                                                   const unsigned short* __restrict__ qlp,
                                                   const unsigned short* __restrict__ khp,
                                                   const unsigned short* __restrict__ klp,
                                                   const unsigned short* __restrict__ vfp,
                                                   float* __restrict__ o) {
  int i = blockIdx.x + blockIdx.y * 16;
  int w = (i & 7) * 64 + (i >> 3);
  int y = w >> 4;
  int widx = w & 15;
  int qt = (widx & 1) ? (widx >> 1) : (15 - (widx >> 1));
  int b = y >> 4, h = y & 15, kvh = h >> 1;
  int wave = threadIdx.x >> 6, lane = threadIdx.x & 63;
  int l15 = lane & 15, g = lane >> 4;
  int q0w = qt * 64 + wave * 16;
  int qglob = q0w + l15;

  __shared__ unsigned short Kh[2][4096], Kl[2][4096];   // bf16 hi/lo, swizzled
  __shared__ unsigned short Vf[2][4096];                // fp16, [d][tok] swizzled
  __shared__ unsigned short Plds[4][16][40];            // fp16 P

  short8 qfh[4], qfl[4];
  {
    const unsigned short* qb = qhp + ((size_t)(b * SEQ + qglob) * NHQ + h) * HDD + g * 8;
    const unsigned short* ql = qlp + ((size_t)(b * SEQ + qglob) * NHQ + h) * HDD + g * 8;
#pragma unroll
    for (int c = 0; c < 4; ++c) {
      qfh[c] = *(const short8*)(qb + c * 32);
      qfl[c] = *(const short8*)(ql + c * 32);
    }
  }

#define STAGE(KV0N, BFN)                                                              \
  {                                                                                   \
    int c0 = wave * 64 + lane;                                                        \
    _Pragma("unroll")                                                                 \
    for (int tch = 0; tch < 2; ++tch) {                                               \
      int c = tch * 256 + c0;                                                         \
      int ki = c >> 4, j = (c & 15) << 4;                                             \
      int js = j ^ ((ki & 7) << 4);                                                   \
      size_t kbase = ((size_t)(b * SEQ + (KV0N) + ki) * NKVH + kvh) * HDD;            \
      GLD_LDS16((const char*)(khp + kbase) + js, &Kh[BFN][c * 8]);                    \
      GLD_LDS16((const char*)(klp + kbase) + js, &Kl[BFN][c * 8]);                    \
      int d = c >> 2, jv = (c & 3) << 4;                                              \
      int jvs = jv ^ ((d & 3) << 4);                                                  \
      size_t vbase = ((size_t)(b * 1024 + kvh * 128 + d)) * SEQ + (KV0N);             \
      GLD_LDS16((const char*)(vfp + vbase) + jvs, &Vf[BFN][c * 8]);                   \
    }                                                                                 \
  }

  f32x4 acc[8] = {};
  float m_run = -INFINITY, l_run = 0.f;
  int nkv = 2 * qt + 2;

  STAGE(0, 0);
  __syncthreads();

  int bf = 0;
  for (int kv = 0; kv < nkv; ++kv) {
    int kv0 = kv * 32;
    if (kv + 1 < nkv) STAGE(kv0 + 32, bf ^ 1);
    bool active = (kv0 <= q0w + 15);
    if (active) {
      // ---- QK^T (bf16 hi/lo, exact) ----
      float sc[2][4];
#pragma unroll
      for (int t = 0; t < 2; ++t) {
        int row = 16 * t + l15;
        int rbyte = row * 256, sw = (row & 7) << 4;
        f32x4 s = {0.f, 0.f, 0.f, 0.f};
#pragma unroll
        for (int c = 0; c < 4; ++c) {
          int off = rbyte + ((c * 64 + g * 16) ^ sw);
          short8 kfh = *(const short8*)((const char*)&Kh[bf][0] + off);
          short8 kfl = *(const short8*)((const char*)&Kl[bf][0] + off);
          s = __builtin_amdgcn_mfma_f32_16x16x32_bf16(kfh, qfh[c], s, 0, 0, 0);
          s = __builtin_amdgcn_mfma_f32_16x16x32_bf16(kfl, qfh[c], s, 0, 0, 0);
          s = __builtin_amdgcn_mfma_f32_16x16x32_bf16(kfh, qfl[c], s, 0, 0, 0);
        }
#pragma unroll
        for (int r = 0; r < 4; ++r) sc[t][r] = s[r];
      }
      if (kv0 + 31 > q0w) {
#pragma unroll
        for (int t = 0; t < 2; ++t)
#pragma unroll
          for (int r = 0; r < 4; ++r)
            if (kv0 + 16 * t + 4 * g + r > qglob) sc[t][r] = -INFINITY;
      }
      // ---- online softmax ----
      float mx = m_run;
#pragma unroll
      for (int t = 0; t < 2; ++t)
#pragma unroll
        for (int r = 0; r < 4; ++r) mx = fmaxf(mx, sc[t][r]);
      mx = fmaxf(mx, __shfl_xor(mx, 16));
      mx = fmaxf(mx, __shfl_xor(mx, 32));
      float corr = __expf(m_run - mx);
      m_run = mx;
      float psum = 0.f;
      unsigned short ph[2][4];
#pragma unroll
      for (int t = 0; t < 2; ++t)
#pragma unroll
        for (int r = 0; r < 4; ++r) {
          float p = __expf(sc[t][r] - mx);
          psum += p;
          ph[t][r] = f2h(p);
        }
      psum += __shfl_xor(psum, 16);
      psum += __shfl_xor(psum, 32);
      l_run = l_run * corr + psum;
      float corro[4];
#pragma unroll
      for (int r = 0; r < 4; ++r) corro[r] = __shfl(corr, 4 * g + r);
#pragma unroll
      for (int dt = 0; dt < 8; ++dt)
#pragma unroll
        for (int r = 0; r < 4; ++r) acc[dt][r] *= corro[r];
      // ---- P transpose through per-wave LDS (fp16) ----
      ushort4 wh;
#pragma unroll
      for (int t = 0; t < 2; ++t) {
        wh.x = ph[t][0]; wh.y = ph[t][1]; wh.z = ph[t][2]; wh.w = ph[t][3];
        *(ushort4*)&Plds[wave][l15][16 * t + 4 * g] = wh;
      }
      half8 pa = s2h(*(const short8*)&Plds[wave][l15][8 * g]);
      // ---- PV (fp16 single) ----
#pragma unroll
      for (int dt = 0; dt < 8; ++dt) {
        int d = dt * 16 + l15;
        int off = d * 64 + ((g * 16) ^ ((d & 3) << 4));
        half8 vf = s2h(*(const short8*)((const char*)&Vf[bf][0] + off));
        acc[dt] = __builtin_amdgcn_mfma_f32_16x16x32_f16(pa, vf, acc[dt], 0, 0, 0);
      }
    }
    __syncthreads();
    bf ^= 1;
  }
#undef STAGE

  float linv = 1.f / l_run;
  float lrow[4];
#pragma unroll
  for (int r = 0; r < 4; ++r) lrow[r] = __shfl(linv, 4 * g + r);
#pragma unroll
  for (int r = 0; r < 4; ++r) {
    size_t orow = ((size_t)(b * SEQ + q0w + 4 * g + r) * NHQ + h) * HDD + l15;
#pragma unroll
    for (int dt = 0; dt < 8; ++dt)
      o[orow + dt * 16] = acc[dt][r] * lrow[r];
  }
}

// ---------------------------------------------------------------------------
extern "C" void kernel_launch(void* const* d_in, const int* in_sizes, int n_in,
                              void* d_out, int out_size, void* d_ws, size_t ws_size,
                              hipStream_t stream) {
  const float* x  = (const float*)d_in[0];
  const float* cs = (const float*)d_in[1];
  const float* sn = (const float*)d_in[2];
  const float* wq = (const float*)d_in[3];
  const float* wk = (const float*)d_in[4];
  const float* wv = (const float*)d_in[5];
  const float* wo = (const float*)d_in[6];
  const float* qn = (const float*)d_in[7];
  const float* kn = (const float*)d_in[8];
  float* out = (float*)d_out;
  char* ws = (char*)d_ws;

  const size_t MB = 1024 * 1024;
  size_t o_xq  = 0;            // 4 MB  int8 xq
  size_t o_wqk = 4  * MB;      // 6 MB  [3072][2048] i8
  size_t o_wvt = 10 * MB;      // 2 MB  [1024][2048] i8
  size_t o_wot = 12 * MB;      // 4 MB  [2048][2048] i8
  size_t o_vt  = 16 * MB;      // 4 MB  fp16 V transposed
  size_t o_qh  = 20 * MB;      // 8 MB
  size_t o_ql  = 28 * MB;      // 8 MB
  size_t o_kh  = 36 * MB;      // 4 MB
  size_t o_kl  = 40 * MB;      // 4 MB
  size_t o_ao  = 44 * MB;      // 16 MB f32 attn out
  size_t o_aq  = 60 * MB;      // 4 MB  int8 requant
  size_t o_as  = 64 * MB;
  size_t o_as2 = o_as  + 8192;
  size_t o_prt = o_as2 + 8192;
  size_t o_wsc = o_prt + 8192;

  signed char* xq  = (signed char*)(ws + o_xq);
  signed char* wqk = (signed char*)(ws + o_wqk);
  signed char* wvt = (signed char*)(ws + o_wvt);
  signed char* wot = (signed char*)(ws + o_wot);
  unsigned short* vt = (unsigned short*)(ws + o_vt);
  unsigned short* qh = (unsigned short*)(ws + o_qh);
  unsigned short* ql = (unsigned short*)(ws + o_ql);
  unsigned short* kh = (unsigned short*)(ws + o_kh);
  unsigned short* kl = (unsigned short*)(ws + o_kl);
  float* ao = (float*)(ws + o_ao);
  signed char* aq = (signed char*)(ws + o_aq);
  float* asx = (float*)(ws + o_as);
  float* as2 = (float*)(ws + o_as2);
  double* prt = (double*)(ws + o_prt);
  float* wsc = (float*)(ws + o_wsc);

  // 1) activation quant of x -> int8
  k_actquant<<<TT, 256, 0, stream>>>(x, xq, asx);

  // 2) weight scales
  k_absum_all<<<dim3(256, 4), 256, 0, stream>>>(wq, wk, wv, wo, prt);
  k_wscale<<<1, 256, 0, stream>>>(prt, wsc);

  // 3) ternary weight quant -> int8
  k_wquant_all<<<2048, 256, 0, stream>>>(wq, wk, wv, wo, wqk, wvt, wot, wsc);

  // 4) fused QKV projection + rmsnorm/rope epilogue (one dispatch)
  k_gemm_i8<<<512, 256, 0, stream>>>(xq, wqk, wvt, 0, nullptr, vt, asx, wsc,
                                     qn, kn, cs, sn, qh, ql, kh, kl);

  // 5) MFMA flash attention
  k_attn_mfma<<<dim3(16, 32), 256, 0, stream>>>(qh, ql, kh, kl, vt, ao);

  // 6) re-quant + output projection
  k_actquant<<<TT, 256, 0, stream>>>(ao, aq, as2);
  k_gemm_i8<<<256, 256, 0, stream>>>(aq, wot, nullptr, 1, out, nullptr, as2, wsc,
                                     nullptr, nullptr, nullptr, nullptr,
                                     nullptr, nullptr, nullptr, nullptr);
}

// Round 7
// 145.320 us; speedup vs baseline: 8.0294x; 1.0987x over previous
//
#include <hip/hip_runtime.h>
#include <hip/hip_bf16.h>

#define TT   2048   // B*S tokens
#define HH   2048   // hidden dim
#define SEQ  1024
#define NHQ  16
#define NKVH 8
#define HDD  128

typedef __attribute__((ext_vector_type(8))) short short8;
typedef __attribute__((ext_vector_type(4))) float f32x4;
typedef __attribute__((ext_vector_type(4))) int int4v;
typedef _Float16 half8 __attribute__((ext_vector_type(8)));

static __device__ __forceinline__ unsigned short f2h(float f) {
  union { _Float16 h; unsigned short u; } c;
  c.h = (_Float16)f;
  return c.u;
}
static __device__ __forceinline__ half8 s2h(short8 v) {
  union { short8 s; half8 h; } c;
  c.s = v;
  return c.h;
}

#define GLD_LDS16(gp, lp)                                                        \
  __builtin_amdgcn_global_load_lds(                                              \
      (const __attribute__((address_space(1))) void*)(const void*)(gp),          \
      (__attribute__((address_space(3))) void*)(void*)(lp), 16, 0, 0)

// ---------------------------------------------------------------------------
// K1: per-row act_quant -> int8 (vectorized float4 loads, shfl reduce)
// ---------------------------------------------------------------------------
__global__ __launch_bounds__(256) void k_actquant(const float* __restrict__ x,
                                                  signed char* __restrict__ xq,
                                                  float* __restrict__ as_inv) {
  int row = blockIdx.x, tid = threadIdx.x;
  int wave = tid >> 6, lane = tid & 63;
  const float4* xr4 = (const float4*)(x + (size_t)row * HH);
  float4 a = xr4[tid * 2], b = xr4[tid * 2 + 1];
  float am = fmaxf(fmaxf(fmaxf(fabsf(a.x), fabsf(a.y)), fmaxf(fabsf(a.z), fabsf(a.w))),
                   fmaxf(fmaxf(fabsf(b.x), fabsf(b.y)), fmaxf(fabsf(b.z), fabsf(b.w))));
#pragma unroll
  for (int o = 32; o; o >>= 1) am = fmaxf(am, __shfl_xor(am, o));
  __shared__ float wred[4];
  if (lane == 0) wred[wave] = am;
  __syncthreads();
  am = fmaxf(fmaxf(wred[0], wred[1]), fmaxf(wred[2], wred[3]));
  am = fmaxf(am, 1e-5f);
  if (tid == 0) as_inv[row] = am / 127.f;
  float scale = 127.f / am;
  float vals[8] = {a.x, a.y, a.z, a.w, b.x, b.y, b.z, b.w};
  unsigned int u0 = 0, u1 = 0;
#pragma unroll
  for (int j = 0; j < 4; ++j) {
    int q = (int)fminf(fmaxf(rintf(vals[j] * scale), -128.f), 127.f);
    u0 |= (unsigned int)(q & 255) << (8 * j);
  }
#pragma unroll
  for (int j = 0; j < 4; ++j) {
    int q = (int)fminf(fmaxf(rintf(vals[4 + j] * scale), -128.f), 127.f);
    u1 |= (unsigned int)(q & 255) << (8 * j);
  }
  uint2 uu; uu.x = u0; uu.y = u1;
  ((uint2*)(xq + (size_t)row * HH))[tid] = uu;
}

// ---------------------------------------------------------------------------
// K2: deterministic partial |w| sums (f64), all 4 weights in one dispatch
// ---------------------------------------------------------------------------
__global__ __launch_bounds__(256) void k_absum_all(const float* __restrict__ wq,
                                                   const float* __restrict__ wk,
                                                   const float* __restrict__ wv,
                                                   const float* __restrict__ wo,
                                                   double* __restrict__ part) {
  int wid = blockIdx.y;
  const float* w = (wid == 0) ? wq : (wid == 1) ? wk : (wid == 2) ? wv : wo;
  int nq = ((wid == 0 || wid == 3) ? 4194304 : 2097152) >> 2;
  double s = 0.0;
  for (int i = blockIdx.x * 256 + threadIdx.x; i < nq; i += 256 * 256) {
    float4 v = ((const float4*)w)[i];
    s += (double)fabsf(v.x) + (double)fabsf(v.y) + (double)fabsf(v.z) + (double)fabsf(v.w);
  }
  __shared__ double red[256];
  red[threadIdx.x] = s;
  __syncthreads();
  for (int st = 128; st > 0; st >>= 1) {
    if (threadIdx.x < st) red[threadIdx.x] += red[threadIdx.x + st];
    __syncthreads();
  }
  if (threadIdx.x == 0) part[wid * 256 + blockIdx.x] = red[0];
}

__global__ __launch_bounds__(256) void k_wscale(const double* __restrict__ part,
                                                float* __restrict__ wsc) {
  __shared__ double red[256];
  const double nvals[4] = {4194304.0, 2097152.0, 2097152.0, 4194304.0};
  for (int w = 0; w < 4; ++w) {
    red[threadIdx.x] = part[w * 256 + threadIdx.x];
    __syncthreads();
    for (int st = 128; st > 0; st >>= 1) {
      if (threadIdx.x < st) red[threadIdx.x] += red[threadIdx.x + st];
      __syncthreads();
    }
    if (threadIdx.x == 0) {
      float mean = (float)(red[0] / nvals[w]);
      wsc[w] = fmaxf(mean, 1e-5f);
    }
    __syncthreads();
  }
}

// ---------------------------------------------------------------------------
// K3: ternary weight quant -> int8, all 4 weights in one dispatch
// ---------------------------------------------------------------------------
__global__ __launch_bounds__(256) void k_wquant_all(const float* __restrict__ wq,
                                                    const float* __restrict__ wk,
                                                    const float* __restrict__ wv,
                                                    const float* __restrict__ wo,
                                                    signed char* __restrict__ wqk,
                                                    signed char* __restrict__ wvt,
                                                    signed char* __restrict__ wot,
                                                    const float* __restrict__ wsc) {
  const int NQ = 3145728;
  for (int qi = blockIdx.x * 256 + threadIdx.x; qi < NQ; qi += gridDim.x * 256) {
    const float* src; signed char* dst; float inv; int off;
    if (qi < 1048576)      { src = wq; dst = wqk;           off = qi;           inv = 1.f / wsc[0]; }
    else if (qi < 1572864) { src = wk; dst = wqk + 4194304; off = qi - 1048576; inv = 1.f / wsc[1]; }
    else if (qi < 2097152) { src = wv; dst = wvt;           off = qi - 1572864; inv = 1.f / wsc[2]; }
    else                   { src = wo; dst = wot;           off = qi - 2097152; inv = 1.f / wsc[3]; }
    float4 v = ((const float4*)src)[off];
    unsigned int u = 0;
    float vv[4] = {v.x, v.y, v.z, v.w};
#pragma unroll
    for (int j = 0; j < 4; ++j) {
      int q = (int)fminf(fmaxf(rintf(vv[j] * inv), -1.f), 1.f);
      u |= (unsigned int)(q & 255) << (8 * j);
    }
    ((unsigned int*)dst)[off] = u;
  }
}

// ---------------------------------------------------------------------------
// K4: i8 MFMA NT-GEMM, 128x128 tile, BK=64, global_load_lds staging,
// source-side XOR swizzle.
// which==0: 512 blocks = 384 QK tiles (fused rmsnorm+rope epilogue -> fp16
//           qf/kf; q scale folds 1/sqrt(128)*log2(e)) + 128 V tiles (fp16
//           transposed vt)
// which==1: 256 blocks, O projection (f32 out, scale wsc[3])
// ---------------------------------------------------------------------------
__global__ __launch_bounds__(256) void k_gemm_i8(const signed char* __restrict__ A0,
                                                 const signed char* __restrict__ B0,
                                                 const signed char* __restrict__ B1,
                                                 int which,
                                                 float* __restrict__ d0,
                                                 unsigned short* __restrict__ dh,
                                                 const float* __restrict__ asx,
                                                 const float* __restrict__ wsc,
                                                 const float* __restrict__ qn,
                                                 const float* __restrict__ kn,
                                                 const float* __restrict__ cs,
                                                 const float* __restrict__ sn,
                                                 unsigned short* __restrict__ qf,
                                                 unsigned short* __restrict__ kf) {
  const int K = HH;
  __shared__ signed char As[8192];   // [128][64] (source-swizzled within rows)
  __shared__ signed char Bs[8192];
  int tid = threadIdx.x;
  int wave = tid >> 6, lane = tid & 63, l15 = lane & 15, g = lane >> 4;
  int wm = wave >> 1, wn = wave & 1;

  const signed char *Ap, *Bp;
  int bm, bn, mode;
  if (which == 0) {
    int gid = (blockIdx.x & 7) * 64 + (blockIdx.x >> 3);   // XCD chunk, 512 blocks
    if (gid < 384) { mode = 0; bm = (gid / 24) * 128; bn = (gid % 24) * 128; Ap = A0; Bp = B0; }
    else { mode = 1; int vid = gid - 384; bm = (vid >> 4) * 128; bn = (vid & 15) * 128; Ap = B1; Bp = A0; }
  } else {
    int gid = (blockIdx.x & 7) * 32 + (blockIdx.x >> 3);   // 256 blocks
    mode = 2; bm = (gid >> 4) * 128; bn = (gid & 15) * 128; Ap = A0; Bp = B0;
  }

  int4v acc[4][4] = {};
  for (int k0 = 0; k0 < K; k0 += 64) {
    __syncthreads();
#pragma unroll
    for (int r = 0; r < 2; ++r) {
      int c = r * 256 + tid;
      int row = c >> 2;
      int kk = ((c & 3) << 4) ^ ((row & 3) << 4);
      GLD_LDS16(Ap + (size_t)(bm + row) * K + k0 + kk, As + c * 16);
      GLD_LDS16(Bp + (size_t)(bn + row) * K + k0 + kk, Bs + c * 16);
    }
    __syncthreads();
    int4v af[4], bf[4];
#pragma unroll
    for (int i = 0; i < 4; ++i) {
      int ra = wm * 64 + i * 16 + l15;
      af[i] = *(const int4v*)&As[ra * 64 + ((g * 16) ^ ((ra & 3) << 4))];
      int rb = (mode == 0) ? (wn * 32 + (i & 1) * 16 + (i >> 1) * 64 + l15)
                           : (wn * 64 + i * 16 + l15);
      bf[i] = *(const int4v*)&Bs[rb * 64 + ((g * 16) ^ ((rb & 3) << 4))];
    }
#pragma unroll
    for (int mi = 0; mi < 4; ++mi)
#pragma unroll
      for (int ni = 0; ni < 4; ++ni)
        acc[mi][ni] = __builtin_amdgcn_mfma_i32_16x16x64_i8(af[mi], bf[ni], acc[mi][ni], 0, 0, 0);
  }

  if (mode == 0) {
    // fused rmsnorm + rope epilogue -> single fp16
    bool isq = (bn < 2048);
    int hh = isq ? (bn >> 7) : ((bn - 2048) >> 7);
    float wN = isq ? wsc[0] : wsc[1];
    float ps = isq ? 0.12751743075f : 1.0f;   // (1/sqrt(128))*log2(e) for q
    const float* nw = isq ? qn : kn;
    unsigned short* oh = isq ? qf : kf;
    int nhp = isq ? NHQ : NKVH;
    float* S = (float*)As;               // reuse LDS: [2][128] f32
    __syncthreads();                     // all waves done reading As/Bs
#pragma unroll
    for (int mi = 0; mi < 4; ++mi) {
#pragma unroll
      for (int rr = 0; rr < 4; ++rr) {
        int tok = bm + wm * 64 + mi * 16 + 4 * g + rr;
        float rs = asx[tok] * wN;
        float ssum = 0.f;
#pragma unroll
        for (int ni = 0; ni < 4; ++ni) {
          float v = (float)acc[mi][ni][rr] * rs;
          ssum += v * v;
        }
        ssum += __shfl_xor(ssum, 1); ssum += __shfl_xor(ssum, 2);
        ssum += __shfl_xor(ssum, 4); ssum += __shfl_xor(ssum, 8);
        if (l15 == 0) S[wn * 128 + wm * 64 + mi * 16 + 4 * g + rr] = ssum;
      }
    }
    __syncthreads();
#pragma unroll
    for (int mi = 0; mi < 4; ++mi) {
#pragma unroll
      for (int rr = 0; rr < 4; ++rr) {
        int rloc = wm * 64 + mi * 16 + 4 * g + rr;
        int tok = bm + rloc;
        float rs = asx[tok] * wN;
        float inv = rsqrtf((S[rloc] + S[128 + rloc]) * (1.f / 128.f) + 1e-6f);
        int s = tok & (SEQ - 1);
        float nv[4];
#pragma unroll
        for (int ni = 0; ni < 4; ++ni) {
          int d = wn * 32 + (ni & 1) * 16 + (ni >> 1) * 64 + l15;
          nv[ni] = nw[d] * ((float)acc[mi][ni][rr] * rs) * inv;
        }
#pragma unroll
        for (int ni = 0; ni < 4; ++ni) {
          int d = wn * 32 + (ni & 1) * 16 + (ni >> 1) * 64 + l15;
          float oo = nv[ni ^ 2];
          float rh = (ni < 2) ? -oo : oo;
          float res = (nv[ni] * cs[s * 128 + d] + rh * sn[s * 128 + d]) * ps;
          size_t oi = ((size_t)tok * nhp + hh) * 128 + d;
          oh[oi] = f2h(res);
        }
      }
    }
  } else if (mode == 2) {
#pragma unroll
    for (int mi = 0; mi < 4; ++mi) {
#pragma unroll
      for (int rr = 0; rr < 4; ++rr) {
        int crow = bm + wm * 64 + mi * 16 + 4 * g + rr;
        float rs = asx[crow] * wsc[3];
#pragma unroll
        for (int ni = 0; ni < 4; ++ni) {
          int ccol = bn + wn * 64 + ni * 16 + l15;
          d0[(size_t)crow * 2048 + ccol] = (float)acc[mi][ni][rr] * rs;
        }
      }
    }
  } else {   // mode 1: V fp16 transposed (crow=feature, ccol=token)
    float w2 = wsc[2];
#pragma unroll
    for (int mi = 0; mi < 4; ++mi) {
#pragma unroll
      for (int rr = 0; rr < 4; ++rr) {
        int crow = bm + wm * 64 + mi * 16 + 4 * g + rr;
#pragma unroll
        for (int ni = 0; ni < 4; ++ni) {
          int ccol = bn + wn * 64 + ni * 16 + l15;
          float v = (float)acc[mi][ni][rr] * asx[ccol] * w2;
          size_t ad = ((size_t)((ccol >> 10) * 1024 + crow)) * 1024 + (ccol & 1023);
          dh[ad] = f2h(v);
        }
      }
    }
  }
}

// ---------------------------------------------------------------------------
// K6: MFMA flash attention, all-fp16 operands (scores carry log2e factor,
// softmax in exp2). 4 waves/block, Q-tile 64, KV tile 32, double-buffered
// LDS staging via global_load_lds (source-side XOR swizzle). Defer-max
// rescale (THR=10 in log2 units). Heavy-first dispatch, XCD-chunked.
// LDS 37888 B -> 4 blocks/CU.
// ---------------------------------------------------------------------------
__global__ __launch_bounds__(256) void k_attn_mfma(const unsigned short* __restrict__ qfp,
                                                   const unsigned short* __restrict__ kfp,
                                                   const unsigned short* __restrict__ vfp,
                                                   float* __restrict__ o) {
  int chunk = blockIdx.x & 7, j = blockIdx.x >> 3;   // XCD, within-chunk
  int qt = 15 - (j >> 2);                            // heavy first in launch order
  int yy = (chunk << 2) + (j & 3);                   // 4 heads/chunk share L2
  int b = yy >> 4, h = yy & 15, kvh = h >> 1;
  int wave = threadIdx.x >> 6, lane = threadIdx.x & 63;
  int l15 = lane & 15, g = lane >> 4;
  int q0w = qt * 64 + wave * 16;
  int qglob = q0w + l15;

  __shared__ unsigned short Kf[2][4096];     // fp16 K, [ki][d] swizzled
  __shared__ unsigned short Vf[2][4096];     // fp16 V^T, [d][tok] swizzled
  __shared__ unsigned short Plds[4][16][40]; // fp16 P transpose buffer

  half8 qf[4];
  {
    const unsigned short* qb = qfp + ((size_t)(b * SEQ + qglob) * NHQ + h) * HDD + g * 8;
#pragma unroll
    for (int c = 0; c < 4; ++c) qf[c] = s2h(*(const short8*)(qb + c * 32));
  }

#define STAGE(KV0N, BFN)                                                              \
  {                                                                                   \
    int c0 = wave * 64 + lane;                                                        \
    _Pragma("unroll")                                                                 \
    for (int tch = 0; tch < 2; ++tch) {                                               \
      int c = tch * 256 + c0;                                                         \
      int ki = c >> 4, jb = (c & 15) << 4;                                            \
      int js = jb ^ ((ki & 7) << 4);                                                  \
      size_t kbase = ((size_t)(b * SEQ + (KV0N) + ki) * NKVH + kvh) * HDD;            \
      GLD_LDS16((const char*)(kfp + kbase) + js, &Kf[BFN][c * 8]);                    \
      int d = c >> 2, jv = (c & 3) << 4;                                              \
      int jvs = jv ^ ((d & 3) << 4);                                                  \
      size_t vbase = ((size_t)(b * 1024 + kvh * 128 + d)) * SEQ + (KV0N);             \
      GLD_LDS16((const char*)(vfp + vbase) + jvs, &Vf[BFN][c * 8]);                   \
    }                                                                                 \
  }

  f32x4 acc[8] = {};
  float m_run = -INFINITY, l_run = 0.f;
  int nkv = 2 * qt + 2;

  STAGE(0, 0);
  __syncthreads();

  int bf = 0;
  for (int kv = 0; kv < nkv; ++kv) {
    int kv0 = kv * 32;
    if (kv + 1 < nkv) STAGE(kv0 + 32, bf ^ 1);
    bool active = (kv0 <= q0w + 15);
    if (active) {
      // ---- QK^T (fp16, scores in log2 units) ----
      float sc[2][4];
      __builtin_amdgcn_s_setprio(1);
#pragma unroll
      for (int t = 0; t < 2; ++t) {
        int row = 16 * t + l15;
        int rbyte = row * 256, sw = (row & 7) << 4;
        f32x4 s = {0.f, 0.f, 0.f, 0.f};
#pragma unroll
        for (int c = 0; c < 4; ++c) {
          int off = rbyte + ((c * 64 + g * 16) ^ sw);
          half8 kf8 = s2h(*(const short8*)((const char*)&Kf[bf][0] + off));
          s = __builtin_amdgcn_mfma_f32_16x16x32_f16(kf8, qf[c], s, 0, 0, 0);
        }
#pragma unroll
        for (int r = 0; r < 4; ++r) sc[t][r] = s[r];
      }
      __builtin_amdgcn_s_setprio(0);
      if (kv0 + 31 > q0w) {
#pragma unroll
        for (int t = 0; t < 2; ++t)
#pragma unroll
          for (int r = 0; r < 4; ++r)
            if (kv0 + 16 * t + 4 * g + r > qglob) sc[t][r] = -INFINITY;
      }
      // ---- online softmax (exp2, defer-max) ----
      float pmax = -INFINITY;
#pragma unroll
      for (int t = 0; t < 2; ++t)
#pragma unroll
        for (int r = 0; r < 4; ++r) pmax = fmaxf(pmax, sc[t][r]);
      pmax = fmaxf(pmax, __shfl_xor(pmax, 16));
      pmax = fmaxf(pmax, __shfl_xor(pmax, 32));
      if (!__all(pmax <= m_run + 10.f)) {
        float mnew = fmaxf(m_run, pmax);
        float corr = exp2f(m_run - mnew);
        m_run = mnew;
        float corro[4];
#pragma unroll
        for (int r = 0; r < 4; ++r) corro[r] = __shfl(corr, 4 * g + r);
#pragma unroll
        for (int dt = 0; dt < 8; ++dt)
#pragma unroll
          for (int r = 0; r < 4; ++r) acc[dt][r] *= corro[r];
        l_run *= corr;
      }
      float psum = 0.f;
      unsigned short ph[2][4];
#pragma unroll
      for (int t = 0; t < 2; ++t)
#pragma unroll
        for (int r = 0; r < 4; ++r) {
          float p = exp2f(sc[t][r] - m_run);
          psum += p;
          ph[t][r] = f2h(p);
        }
      psum += __shfl_xor(psum, 16);
      psum += __shfl_xor(psum, 32);
      l_run += psum;
      // ---- P transpose through per-wave LDS (fp16) ----
      ushort4 wh;
#pragma unroll
      for (int t = 0; t < 2; ++t) {
        wh.x = ph[t][0]; wh.y = ph[t][1]; wh.z = ph[t][2]; wh.w = ph[t][3];
        *(ushort4*)&Plds[wave][l15][16 * t + 4 * g] = wh;
      }
      half8 pa = s2h(*(const short8*)&Plds[wave][l15][8 * g]);
      // ---- PV (fp16) ----
      __builtin_amdgcn_s_setprio(1);
#pragma unroll
      for (int dt = 0; dt < 8; ++dt) {
        int d = dt * 16 + l15;
        int off = d * 64 + ((g * 16) ^ ((d & 3) << 4));
        half8 vf8 = s2h(*(const short8*)((const char*)&Vf[bf][0] + off));
        acc[dt] = __builtin_amdgcn_mfma_f32_16x16x32_f16(pa, vf8, acc[dt], 0, 0, 0);
      }
      __builtin_amdgcn_s_setprio(0);
    }
    __syncthreads();
    bf ^= 1;
  }
#undef STAGE

  float linv = 1.f / l_run;
  float lrow[4];
#pragma unroll
  for (int r = 0; r < 4; ++r) lrow[r] = __shfl(linv, 4 * g + r);
#pragma unroll
  for (int r = 0; r < 4; ++r) {
    size_t orow = ((size_t)(b * SEQ + q0w + 4 * g + r) * NHQ + h) * HDD + l15;
#pragma unroll
    for (int dt = 0; dt < 8; ++dt)
      o[orow + dt * 16] = acc[dt][r] * lrow[r];
  }
}

// ---------------------------------------------------------------------------
extern "C" void kernel_launch(void* const* d_in, const int* in_sizes, int n_in,
                              void* d_out, int out_size, void* d_ws, size_t ws_size,
                              hipStream_t stream) {
  const float* x  = (const float*)d_in[0];
  const float* cs = (const float*)d_in[1];
  const float* sn = (const float*)d_in[2];
  const float* wq = (const float*)d_in[3];
  const float* wk = (const float*)d_in[4];
  const float* wv = (const float*)d_in[5];
  const float* wo = (const float*)d_in[6];
  const float* qn = (const float*)d_in[7];
  const float* kn = (const float*)d_in[8];
  float* out = (float*)d_out;
  char* ws = (char*)d_ws;

  const size_t MB = 1024 * 1024;
  size_t o_xq  = 0;            // 4 MB  int8 xq
  size_t o_wqk = 4  * MB;      // 6 MB  [3072][2048] i8
  size_t o_wvt = 10 * MB;      // 2 MB  [1024][2048] i8
  size_t o_wot = 12 * MB;      // 4 MB  [2048][2048] i8
  size_t o_vt  = 16 * MB;      // 4 MB  fp16 V transposed
  size_t o_qf  = 20 * MB;      // 8 MB  fp16 q (rope'd, log2e/sqrt(128) folded)
  size_t o_kf  = 28 * MB;      // 4 MB  fp16 k (rope'd)
  size_t o_ao  = 32 * MB;      // 16 MB f32 attn out
  size_t o_aq  = 48 * MB;      // 4 MB  int8 requant
  size_t o_as  = 52 * MB;
  size_t o_as2 = o_as  + 8192;
  size_t o_prt = o_as2 + 8192;
  size_t o_wsc = o_prt + 8192;

  signed char* xq  = (signed char*)(ws + o_xq);
  signed char* wqk = (signed char*)(ws + o_wqk);
  signed char* wvt = (signed char*)(ws + o_wvt);
  signed char* wot = (signed char*)(ws + o_wot);
  unsigned short* vt = (unsigned short*)(ws + o_vt);
  unsigned short* qf = (unsigned short*)(ws + o_qf);
  unsigned short* kf = (unsigned short*)(ws + o_kf);
  float* ao = (float*)(ws + o_ao);
  signed char* aq = (signed char*)(ws + o_aq);
  float* asx = (float*)(ws + o_as);
  float* as2 = (float*)(ws + o_as2);
  double* prt = (double*)(ws + o_prt);
  float* wsc = (float*)(ws + o_wsc);

  // 1) activation quant of x -> int8
  k_actquant<<<TT, 256, 0, stream>>>(x, xq, asx);

  // 2) weight scales
  k_absum_all<<<dim3(256, 4), 256, 0, stream>>>(wq, wk, wv, wo, prt);
  k_wscale<<<1, 256, 0, stream>>>(prt, wsc);

  // 3) ternary weight quant -> int8
  k_wquant_all<<<2048, 256, 0, stream>>>(wq, wk, wv, wo, wqk, wvt, wot, wsc);

  // 4) fused QKV projection + rmsnorm/rope epilogue (one dispatch)
  k_gemm_i8<<<512, 256, 0, stream>>>(xq, wqk, wvt, 0, nullptr, vt, asx, wsc,
                                     qn, kn, cs, sn, qf, kf);

  // 5) MFMA flash attention (all fp16 operands)
  k_attn_mfma<<<512, 256, 0, stream>>>(qf, kf, vt, ao);

  // 6) re-quant + output projection
  k_actquant<<<TT, 256, 0, stream>>>(ao, aq, as2);
  k_gemm_i8<<<256, 256, 0, stream>>>(aq, wot, nullptr, 1, out, nullptr, as2, wsc,
                                     nullptr, nullptr, nullptr, nullptr,
                                     nullptr, nullptr);
}